// Round 1
// baseline (5393.174 us; speedup 1.0000x reference)
//
#include <hip/hip_runtime.h>
#include <cstdint>

#define N_NODES 50000
#define N_EDGES 400000
#define IN_DIM 512
#define HID 512
#define HID2 256
#define NUM_GRAPHS 500

// ---------------------------------------------------------------------------
// GEMM: C[M,N] (row-major, ld=N) = A[M,K] (row-major) * B[N,K]^T (row-major)
// i.e. C[m][n] = sum_k A[m][k] * B[n][k]   (both operands K-contiguous)
// 64x64 tile, BK=16, 256 threads, 4x4 per-thread micro-tile, fp32.
// ---------------------------------------------------------------------------
template <int BM, int BN, int BK>
__global__ __launch_bounds__(256) void gemm_btn(const float* __restrict__ A,
                                                const float* __restrict__ B,
                                                float* __restrict__ C,
                                                int M, int N, int K) {
  __shared__ float As[BK][BM + 4];
  __shared__ float Bs[BK][BN + 4];
  const int bm = blockIdx.x * BM;
  const int bn = blockIdx.y * BN;
  const int tid = threadIdx.x;
  const int tm = (tid >> 4) * 4;   // 0..60
  const int tn = (tid & 15) * 4;   // 0..60
  const int lr = tid >> 2;         // 0..63 : row within tile for loads
  const int lc = (tid & 3) * 4;    // 0,4,8,12 : k-offset for float4 load
  float acc[4][4] = {};

  for (int k0 = 0; k0 < K; k0 += BK) {
    float4 a4 = make_float4(0.f, 0.f, 0.f, 0.f);
    const int ar = bm + lr;
    if (ar < M) a4 = *(const float4*)(A + (size_t)ar * K + k0 + lc);
    const float4 b4 = *(const float4*)(B + (size_t)(bn + lr) * K + k0 + lc);
    __syncthreads();
    As[lc + 0][lr] = a4.x; As[lc + 1][lr] = a4.y;
    As[lc + 2][lr] = a4.z; As[lc + 3][lr] = a4.w;
    Bs[lc + 0][lr] = b4.x; Bs[lc + 1][lr] = b4.y;
    Bs[lc + 2][lr] = b4.z; Bs[lc + 3][lr] = b4.w;
    __syncthreads();
#pragma unroll
    for (int k = 0; k < BK; ++k) {
      const float4 av = *(const float4*)&As[k][tm];
      const float4 bv = *(const float4*)&Bs[k][tn];
      const float am[4] = {av.x, av.y, av.z, av.w};
      const float bn_[4] = {bv.x, bv.y, bv.z, bv.w};
#pragma unroll
      for (int i = 0; i < 4; ++i)
#pragma unroll
        for (int j = 0; j < 4; ++j)
          acc[i][j] += am[i] * bn_[j];
    }
  }

#pragma unroll
  for (int i = 0; i < 4; ++i) {
    const int row = bm + tm + i;
    if (row < M) {
      float4 v = make_float4(acc[i][0], acc[i][1], acc[i][2], acc[i][3]);
      *(float4*)(C + (size_t)row * N + bn + tn) = v;
    }
  }
}

// ---------------------------------------------------------------------------
// Edge scatter: agg[dst[e]] += feat[src[e]]  (one wave per edge, float4 rows)
// ---------------------------------------------------------------------------
template <int D>
__global__ __launch_bounds__(256) void scatter_add(const float* __restrict__ feat,
                                                   const int* __restrict__ src,
                                                   const int* __restrict__ dst,
                                                   float* __restrict__ agg, int nE) {
  const int e = (int)((blockIdx.x * 256u + threadIdx.x) >> 6);
  if (e >= nE) return;
  const int lane = threadIdx.x & 63;
  const float* sp = feat + (size_t)src[e] * D;
  float* dp = agg + (size_t)dst[e] * D;
#pragma unroll
  for (int i = lane * 4; i < D; i += 256) {
    const float4 v = *(const float4*)(sp + i);
    atomicAdd(dp + i + 0, v.x);
    atomicAdd(dp + i + 1, v.y);
    atomicAdd(dp + i + 2, v.z);
    atomicAdd(dp + i + 3, v.w);
  }
}

__global__ void deg_kernel(const int* __restrict__ dst, float* __restrict__ deg, int nE) {
  const int e = blockIdx.x * 256 + threadIdx.x;
  if (e < nE) atomicAdd(deg + dst[e], 1.0f);
}

__global__ void counts_kernel(const int* __restrict__ batch, float* __restrict__ counts, int n) {
  const int i = blockIdx.x * 256 + threadIdx.x;
  if (i < n) atomicAdd(counts + batch[i], 1.0f);
}

// ---------------------------------------------------------------------------
// h = relu(agg / max(deg,1) + bias + r)   -- in place on agg
// ---------------------------------------------------------------------------
template <int D>
__global__ __launch_bounds__(256) void combine_kernel(float* __restrict__ aggh,
                                                      const float* __restrict__ r,
                                                      const float* __restrict__ bias,
                                                      const float* __restrict__ deg,
                                                      int N) {
  constexpr int V = D / 4;
  const size_t t = (size_t)blockIdx.x * 256 + threadIdx.x;
  if (t >= (size_t)N * V) return;
  const int n = (int)(t / V);
  const int o = (int)(t % V) * 4;
  const float invd = 1.0f / fmaxf(deg[n], 1.0f);
  float4 a = *(float4*)(aggh + (size_t)n * D + o);
  const float4 rv = *(const float4*)(r + (size_t)n * D + o);
  const float4 b = *(const float4*)(bias + o);
  a.x = fmaxf(fmaf(a.x, invd, b.x + rv.x), 0.f);
  a.y = fmaxf(fmaf(a.y, invd, b.y + rv.y), 0.f);
  a.z = fmaxf(fmaf(a.z, invd, b.z + rv.z), 0.f);
  a.w = fmaxf(fmaf(a.w, invd, b.w + rv.w), 0.f);
  *(float4*)(aggh + (size_t)n * D + o) = a;
}

// ---------------------------------------------------------------------------
// pooled[batch[n]] += h[n]
// ---------------------------------------------------------------------------
template <int D>
__global__ __launch_bounds__(256) void pool_kernel(const float* __restrict__ h,
                                                   const int* __restrict__ batch,
                                                   float* __restrict__ pooled, int N) {
  constexpr int V = D / 4;
  const size_t t = (size_t)blockIdx.x * 256 + threadIdx.x;
  if (t >= (size_t)N * V) return;
  const int n = (int)(t / V);
  const int o = (int)(t % V) * 4;
  const int g = batch[n];
  const float4 v = *(const float4*)(h + (size_t)n * D + o);
  float* pp = pooled + (size_t)g * D + o;
  atomicAdd(pp + 0, v.x);
  atomicAdd(pp + 1, v.y);
  atomicAdd(pp + 2, v.z);
  atomicAdd(pp + 3, v.w);
}

// ---------------------------------------------------------------------------
// logits = (pooled_sum / counts) @ Wfc^T + bfc ; log_softmax over 2 classes
// one wave per graph
// ---------------------------------------------------------------------------
__global__ __launch_bounds__(64) void final_kernel(const float* __restrict__ pooled,
                                                   const float* __restrict__ counts,
                                                   const float* __restrict__ Wfc,
                                                   const float* __restrict__ bfc,
                                                   float* __restrict__ out) {
  const int g = blockIdx.x;
  const int lane = threadIdx.x;
  const float* p = pooled + (size_t)g * HID2;
  float a0 = 0.f, a1 = 0.f;
#pragma unroll
  for (int i = lane; i < HID2; i += 64) {
    const float v = p[i];
    a0 += v * Wfc[i];
    a1 += v * Wfc[HID2 + i];
  }
#pragma unroll
  for (int off = 32; off > 0; off >>= 1) {
    a0 += __shfl_down(a0, off);
    a1 += __shfl_down(a1, off);
  }
  if (lane == 0) {
    const float c = fmaxf(counts[g], 1.0f);
    const float l0 = a0 / c + bfc[0];
    const float l1 = a1 / c + bfc[1];
    const float m = fmaxf(l0, l1);
    const float lse = m + logf(expf(l0 - m) + expf(l1 - m));
    out[g * 2 + 0] = l0 - lse;
    out[g * 2 + 1] = l1 - lse;
  }
}

extern "C" void kernel_launch(void* const* d_in, const int* in_sizes, int n_in,
                              void* d_out, int out_size, void* d_ws, size_t ws_size,
                              hipStream_t stream) {
  (void)in_sizes; (void)n_in; (void)out_size; (void)ws_size;
  const float* x   = (const float*)d_in[0];
  const int* eidx  = (const int*)d_in[1];
  const int* batch = (const int*)d_in[2];
  const float* W1l = (const float*)d_in[3];
  const float* b1  = (const float*)d_in[4];
  const float* W1r = (const float*)d_in[5];
  const float* W2l = (const float*)d_in[6];
  const float* b2  = (const float*)d_in[7];
  const float* W2r = (const float*)d_in[8];
  const float* Wfc = (const float*)d_in[9];
  const float* bfc = (const float*)d_in[10];
  float* out = (float*)d_out;
  const int* src = eidx;
  const int* dst = eidx + N_EDGES;

  // workspace carve-up
  char* ws = (char*)d_ws;
  size_t off = 0;
  auto alloc = [&](size_t bytes) {
    char* p = ws + off;
    off += (bytes + 255) & ~(size_t)255;
    return p;
  };
  float* bufT   = (float*)alloc((size_t)N_NODES * HID * 4);   // t = h @ Wl^T
  float* bufR   = (float*)alloc((size_t)N_NODES * HID * 4);   // r = h @ Wr^T
  float* aggH   = (float*)alloc((size_t)N_NODES * HID * 4);   // agg, then h (in place)
  float* deg    = (float*)alloc((size_t)N_NODES * 4);
  float* pooled = (float*)alloc((size_t)NUM_GRAPHS * HID2 * 4);
  float* counts = (float*)alloc((size_t)NUM_GRAPHS * 4);

  // zero accumulators (ws is poisoned 0xAA; must re-init every launch)
  hipMemsetAsync(aggH, 0, (size_t)N_NODES * HID * 4, stream);
  hipMemsetAsync(deg, 0, (size_t)N_NODES * 4, stream);
  hipMemsetAsync(pooled, 0, (size_t)NUM_GRAPHS * HID2 * 4, stream);
  hipMemsetAsync(counts, 0, (size_t)NUM_GRAPHS * 4, stream);

  deg_kernel<<<(N_EDGES + 255) / 256, 256, 0, stream>>>(dst, deg, N_EDGES);
  counts_kernel<<<(N_NODES + 255) / 256, 256, 0, stream>>>(batch, counts, N_NODES);

  // ---- layer 1: h1 = relu(mean_agg(x@W1l^T) + b1 + x@W1r^T) ----
  {
    dim3 grid((N_NODES + 63) / 64, HID / 64);
    gemm_btn<64, 64, 16><<<grid, 256, 0, stream>>>(x, W1l, bufT, N_NODES, HID, IN_DIM);
    gemm_btn<64, 64, 16><<<grid, 256, 0, stream>>>(x, W1r, bufR, N_NODES, HID, IN_DIM);
  }
  scatter_add<HID><<<(N_EDGES + 3) / 4, 256, 0, stream>>>(bufT, src, dst, aggH, N_EDGES);
  combine_kernel<HID><<<(N_NODES * (HID / 4) + 255) / 256, 256, 0, stream>>>(
      aggH, bufR, b1, deg, N_NODES);
  // aggH now holds h1 [N_NODES, HID]

  // ---- layer 2: h2 = relu(mean_agg(h1@W2l^T) + b2 + h1@W2r^T) ----
  {
    dim3 grid((N_NODES + 63) / 64, HID2 / 64);
    gemm_btn<64, 64, 16><<<grid, 256, 0, stream>>>(aggH, W2l, bufT, N_NODES, HID2, HID);
    gemm_btn<64, 64, 16><<<grid, 256, 0, stream>>>(aggH, W2r, bufR, N_NODES, HID2, HID);
  }
  // h1 no longer needed; reuse aggH front for 256-dim agg2 (in-place h2)
  hipMemsetAsync(aggH, 0, (size_t)N_NODES * HID2 * 4, stream);
  scatter_add<HID2><<<(N_EDGES + 3) / 4, 256, 0, stream>>>(bufT, src, dst, aggH, N_EDGES);
  combine_kernel<HID2><<<(N_NODES * (HID2 / 4) + 255) / 256, 256, 0, stream>>>(
      aggH, bufR, b2, deg, N_NODES);
  // aggH now holds h2 [N_NODES, HID2]

  pool_kernel<HID2><<<(N_NODES * (HID2 / 4) + 255) / 256, 256, 0, stream>>>(
      aggH, batch, pooled, N_NODES);
  final_kernel<<<NUM_GRAPHS, 64, 0, stream>>>(pooled, counts, Wfc, bfc, out);
}

// Round 2
// 1467.649 us; speedup vs baseline: 3.6747x; 3.6747x over previous
//
#include <hip/hip_runtime.h>
#include <cstdint>

#define N_NODES 50000
#define N_EDGES 400000
#define IN_DIM 512
#define HID 512
#define HID2 256
#define NUM_GRAPHS 500

// ---------------------------------------------------------------------------
// GEMM: C[M,N] = A[M,K] * B[N,K]^T  (row-major, both K-contiguous), fp32
// 64x64 tile, BK=16, 256 threads, 4x4 micro-tile.
// ---------------------------------------------------------------------------
template <int BM, int BN, int BK>
__global__ __launch_bounds__(256) void gemm_btn(const float* __restrict__ A,
                                                const float* __restrict__ B,
                                                float* __restrict__ C,
                                                int M, int N, int K) {
  __shared__ float As[BK][BM + 4];
  __shared__ float Bs[BK][BN + 4];
  const int bm = blockIdx.x * BM;
  const int bn = blockIdx.y * BN;
  const int tid = threadIdx.x;
  const int tm = (tid >> 4) * 4;
  const int tn = (tid & 15) * 4;
  const int lr = tid >> 2;
  const int lc = (tid & 3) * 4;
  float acc[4][4] = {};

  for (int k0 = 0; k0 < K; k0 += BK) {
    float4 a4 = make_float4(0.f, 0.f, 0.f, 0.f);
    const int ar = bm + lr;
    if (ar < M) a4 = *(const float4*)(A + (size_t)ar * K + k0 + lc);
    const float4 b4 = *(const float4*)(B + (size_t)(bn + lr) * K + k0 + lc);
    __syncthreads();
    As[lc + 0][lr] = a4.x; As[lc + 1][lr] = a4.y;
    As[lc + 2][lr] = a4.z; As[lc + 3][lr] = a4.w;
    Bs[lc + 0][lr] = b4.x; Bs[lc + 1][lr] = b4.y;
    Bs[lc + 2][lr] = b4.z; Bs[lc + 3][lr] = b4.w;
    __syncthreads();
#pragma unroll
    for (int k = 0; k < BK; ++k) {
      const float4 av = *(const float4*)&As[k][tm];
      const float4 bv = *(const float4*)&Bs[k][tn];
      const float am[4] = {av.x, av.y, av.z, av.w};
      const float bn_[4] = {bv.x, bv.y, bv.z, bv.w};
#pragma unroll
      for (int i = 0; i < 4; ++i)
#pragma unroll
        for (int j = 0; j < 4; ++j)
          acc[i][j] += am[i] * bn_[j];
    }
  }

#pragma unroll
  for (int i = 0; i < 4; ++i) {
    const int row = bm + tm + i;
    if (row < M) {
      float4 v = make_float4(acc[i][0], acc[i][1], acc[i][2], acc[i][3]);
      *(float4*)(C + (size_t)row * N + bn + tn) = v;
    }
  }
}

// ---------------------------------------------------------------------------
// CSR build
// ---------------------------------------------------------------------------
__global__ void deg_hist(const int* __restrict__ dst, int* __restrict__ degi, int nE) {
  const int e = blockIdx.x * 256 + threadIdx.x;
  if (e < nE) atomicAdd(&degi[dst[e]], 1);
}

// single-workgroup exclusive scan of degi[0..n) -> offs[0..n], offs[n]=total
__global__ __launch_bounds__(1024) void scan_kernel(const int* __restrict__ degi,
                                                    int* __restrict__ offs, int n) {
  __shared__ int sums[1024];
  const int tid = threadIdx.x;
  const int C = (n + 1023) / 1024;
  const int base = tid * C;
  int local = 0;
  for (int i = 0; i < C; ++i) {
    const int idx = base + i;
    if (idx < n) local += degi[idx];
  }
  sums[tid] = local;
  __syncthreads();
  for (int off = 1; off < 1024; off <<= 1) {
    const int v = (tid >= off) ? sums[tid - off] : 0;
    __syncthreads();
    sums[tid] += v;
    __syncthreads();
  }
  int run = (tid == 0) ? 0 : sums[tid - 1];
  for (int i = 0; i < C; ++i) {
    const int idx = base + i;
    if (idx < n) { offs[idx] = run; run += degi[idx]; }
  }
  if (tid == 1023) offs[n] = sums[1023];
}

__global__ void fill_csr(const int* __restrict__ src, const int* __restrict__ dst,
                         const int* __restrict__ offs, int* __restrict__ cursor,
                         int* __restrict__ sorted_src, int nE) {
  const int e = blockIdx.x * 256 + threadIdx.x;
  if (e < nE) {
    const int d = dst[e];
    const int pos = offs[d] + atomicAdd(&cursor[d], 1);
    sorted_src[pos] = src[e];
  }
}

// ---------------------------------------------------------------------------
// h[n] = relu( mean_{e in CSR(n)} t[src_e]  + bias + r[n] )
// one node per D/4-lane group; fully fused epilogue, no atomics.
// ---------------------------------------------------------------------------
template <int D, int NPB>
__global__ __launch_bounds__(NPB * (D / 4)) void gather_combine(
    const float* __restrict__ t, const float* __restrict__ r,
    const float* __restrict__ bias, const int* __restrict__ offs,
    const int* __restrict__ sorted_src, float* __restrict__ h, int N) {
  constexpr int LANES = D / 4;
  const int node = blockIdx.x * NPB + (int)(threadIdx.x / LANES);
  if (node >= N) return;
  const int o = (int)(threadIdx.x % LANES) * 4;
  const int beg = offs[node];
  const int end = offs[node + 1];
  float ax = 0.f, ay = 0.f, az = 0.f, aw = 0.f;
  for (int e = beg; e < end; ++e) {
    const int s = sorted_src[e];
    const float4 v = *(const float4*)(t + (size_t)s * D + o);
    ax += v.x; ay += v.y; az += v.z; aw += v.w;
  }
  const float invd = 1.0f / fmaxf((float)(end - beg), 1.0f);
  const float4 rv = *(const float4*)(r + (size_t)node * D + o);
  const float4 bv = *(const float4*)(bias + o);
  float4 hv;
  hv.x = fmaxf(fmaf(ax, invd, bv.x + rv.x), 0.f);
  hv.y = fmaxf(fmaf(ay, invd, bv.y + rv.y), 0.f);
  hv.z = fmaxf(fmaf(az, invd, bv.z + rv.z), 0.f);
  hv.w = fmaxf(fmaf(aw, invd, bv.w + rv.w), 0.f);
  *(float4*)(h + (size_t)node * D + o) = hv;
}

// ---------------------------------------------------------------------------
// Fused pool + FC + log_softmax. batch is SORTED -> each graph's nodes are a
// contiguous range; binary search the range, sum columns, reduce dot products.
// one 256-thread block per graph.
// ---------------------------------------------------------------------------
__global__ __launch_bounds__(256) void pool_final(const float* __restrict__ h,
                                                  const int* __restrict__ batch,
                                                  const float* __restrict__ Wfc,
                                                  const float* __restrict__ bfc,
                                                  float* __restrict__ out, int nNodes) {
  const int g = blockIdx.x;
  __shared__ int sbeg, send;
  if (threadIdx.x == 0) {
    int lo = 0, hi = nNodes;
    while (lo < hi) { const int mid = (lo + hi) >> 1; if (batch[mid] < g) lo = mid + 1; else hi = mid; }
    sbeg = lo;
    hi = nNodes;
    while (lo < hi) { const int mid = (lo + hi) >> 1; if (batch[mid] < g + 1) lo = mid + 1; else hi = mid; }
    send = lo;
  }
  __syncthreads();
  const int t = threadIdx.x;
  float s = 0.f;
  for (int row = sbeg; row < send; ++row) s += h[(size_t)row * HID2 + t];
  const float cnt = fmaxf((float)(send - sbeg), 1.0f);
  const float p = s / cnt;
  float d0 = p * Wfc[t];
  float d1 = p * Wfc[HID2 + t];
#pragma unroll
  for (int off = 32; off > 0; off >>= 1) {
    d0 += __shfl_down(d0, off);
    d1 += __shfl_down(d1, off);
  }
  __shared__ float r0[4], r1[4];
  const int wid = t >> 6, lane = t & 63;
  if (lane == 0) { r0[wid] = d0; r1[wid] = d1; }
  __syncthreads();
  if (t == 0) {
    const float l0 = r0[0] + r0[1] + r0[2] + r0[3] + bfc[0];
    const float l1 = r1[0] + r1[1] + r1[2] + r1[3] + bfc[1];
    const float m = fmaxf(l0, l1);
    const float lse = m + logf(expf(l0 - m) + expf(l1 - m));
    out[g * 2 + 0] = l0 - lse;
    out[g * 2 + 1] = l1 - lse;
  }
}

extern "C" void kernel_launch(void* const* d_in, const int* in_sizes, int n_in,
                              void* d_out, int out_size, void* d_ws, size_t ws_size,
                              hipStream_t stream) {
  (void)in_sizes; (void)n_in; (void)out_size; (void)ws_size;
  const float* x   = (const float*)d_in[0];
  const int* eidx  = (const int*)d_in[1];
  const int* batch = (const int*)d_in[2];
  const float* W1l = (const float*)d_in[3];
  const float* b1  = (const float*)d_in[4];
  const float* W1r = (const float*)d_in[5];
  const float* W2l = (const float*)d_in[6];
  const float* b2  = (const float*)d_in[7];
  const float* W2r = (const float*)d_in[8];
  const float* Wfc = (const float*)d_in[9];
  const float* bfc = (const float*)d_in[10];
  float* out = (float*)d_out;
  const int* src = eidx;
  const int* dst = eidx + N_EDGES;

  char* ws = (char*)d_ws;
  size_t off = 0;
  auto alloc = [&](size_t bytes) {
    char* p = ws + off;
    off += (bytes + 255) & ~(size_t)255;
    return p;
  };
  float* bufT = (float*)alloc((size_t)N_NODES * HID * 4);  // t = h @ Wl^T
  float* bufR = (float*)alloc((size_t)N_NODES * HID * 4);  // r = h @ Wr^T
  float* bufH = (float*)alloc((size_t)N_NODES * HID * 4);  // h1 then h2
  int* degi       = (int*)alloc((size_t)N_NODES * 4);
  int* offs       = (int*)alloc((size_t)(N_NODES + 1) * 4);
  int* cursor     = (int*)alloc((size_t)N_NODES * 4);
  int* sorted_src = (int*)alloc((size_t)N_EDGES * 4);

  // CSR build (ws is poisoned; zero the two accumulating int arrays)
  hipMemsetAsync(degi, 0, (size_t)N_NODES * 4, stream);
  hipMemsetAsync(cursor, 0, (size_t)N_NODES * 4, stream);
  deg_hist<<<(N_EDGES + 255) / 256, 256, 0, stream>>>(dst, degi, N_EDGES);
  scan_kernel<<<1, 1024, 0, stream>>>(degi, offs, N_NODES);
  fill_csr<<<(N_EDGES + 255) / 256, 256, 0, stream>>>(src, dst, offs, cursor,
                                                      sorted_src, N_EDGES);

  // ---- layer 1 ----
  {
    dim3 grid((N_NODES + 63) / 64, HID / 64);
    gemm_btn<64, 64, 16><<<grid, 256, 0, stream>>>(x, W1l, bufT, N_NODES, HID, IN_DIM);
    gemm_btn<64, 64, 16><<<grid, 256, 0, stream>>>(x, W1r, bufR, N_NODES, HID, IN_DIM);
  }
  gather_combine<HID, 1><<<N_NODES, HID / 4, 0, stream>>>(
      bufT, bufR, b1, offs, sorted_src, bufH, N_NODES);

  // ---- layer 2 ----
  {
    dim3 grid((N_NODES + 63) / 64, HID2 / 64);
    gemm_btn<64, 64, 16><<<grid, 256, 0, stream>>>(bufH, W2l, bufT, N_NODES, HID2, HID);
    gemm_btn<64, 64, 16><<<grid, 256, 0, stream>>>(bufH, W2r, bufR, N_NODES, HID2, HID);
  }
  gather_combine<HID2, 2><<<(N_NODES + 1) / 2, 2 * (HID2 / 4), 0, stream>>>(
      bufT, bufR, b2, offs, sorted_src, bufH, N_NODES);

  // ---- pool + fc + log_softmax ----
  pool_final<<<NUM_GRAPHS, 256, 0, stream>>>(bufH, batch, Wfc, bfc, out, N_NODES);
}

// Round 3
// 466.032 us; speedup vs baseline: 11.5725x; 3.1492x over previous
//
#include <hip/hip_runtime.h>
#include <cstdint>

#define N_NODES 50000
#define N_PAD 50048  // 391 * 128
#define N_EDGES 400000
#define IN_DIM 512
#define HID 512
#define HID2 256
#define NUM_GRAPHS 500

typedef unsigned short u16;
typedef short s8v __attribute__((ext_vector_type(8)));    // 8 bf16 for MFMA A/B
typedef float f4v __attribute__((ext_vector_type(4)));    // MFMA C/D
typedef u16 u16x8 __attribute__((ext_vector_type(8)));

__device__ __forceinline__ u16 f2bf(float f) {
  union { float f; uint32_t u; } c;
  c.f = f;
  const uint32_t u = c.u;
  return (u16)((u + 0x7fffu + ((u >> 16) & 1u)) >> 16);  // RNE
}
__device__ __forceinline__ float bf2f(u16 v) {
  union { uint32_t u; float f; } c;
  c.u = ((uint32_t)v) << 16;
  return c.f;
}

// global -> LDS async, 16B per lane. LDS dest = wave-uniform base + lane*16.
__device__ __forceinline__ void gload16(const void* g, void* l) {
  __builtin_amdgcn_global_load_lds(
      (const __attribute__((address_space(1))) void*)(uintptr_t)g,
      (__attribute__((address_space(3))) void*)(uint32_t)(uintptr_t)l, 16, 0, 0);
}

// ---------------------------------------------------------------------------
// fp32 -> bf16 flat convert (8 elems/thread)
// ---------------------------------------------------------------------------
__global__ __launch_bounds__(256) void cvt_f32_bf16(const float* __restrict__ in,
                                                    u16* __restrict__ out, int n8) {
  const int i = blockIdx.x * 256 + threadIdx.x;
  if (i >= n8) return;
  const float4 a = ((const float4*)in)[2 * i];
  const float4 b = ((const float4*)in)[2 * i + 1];
  u16x8 o;
  o[0] = f2bf(a.x); o[1] = f2bf(a.y); o[2] = f2bf(a.z); o[3] = f2bf(a.w);
  o[4] = f2bf(b.x); o[5] = f2bf(b.y); o[6] = f2bf(b.z); o[7] = f2bf(b.w);
  ((u16x8*)out)[i] = o;
}

// ---------------------------------------------------------------------------
// bf16 MFMA GEMM, m97 structure: C[M,N](bf16) = A[M,K](bf16) * B[N,K]^T(bf16)
// 128x128 tile, BK=32, 256 thr (4 waves, 2x2), 4x4 frags of 16x16x32.
// M, N assumed multiples of 128 (buffers padded). lda = K.
// ---------------------------------------------------------------------------
__global__ __launch_bounds__(256) void gemm_mfma(const u16* __restrict__ A,
                                                 const u16* __restrict__ B,
                                                 u16* __restrict__ C,
                                                 int K, int ldc) {
  __shared__ __align__(16) u16 As[128 * 32];
  __shared__ __align__(16) u16 Bs[128 * 32];
  const int tid = threadIdx.x;
  const int lane = tid & 63;
  const int wave = tid >> 6;
  const int wr = (wave >> 1) * 64;   // wave row offset in tile
  const int wc = (wave & 1) * 64;    // wave col offset in tile
  const int fr = lane & 15;          // fragment row/col within 16x16
  const int fq = lane >> 4;          // quad 0..3
  const size_t bm = (size_t)blockIdx.x * 128;
  const size_t bn = (size_t)blockIdx.y * 128;

  // staging: 256 threads x 2 x 16B per operand tile (128 rows x 32 bf16)
  const int r0 = tid >> 2;           // 0..63
  const int c0 = (tid & 3) * 8;      // 0,8,16,24
  const u16* gA = A + (bm + r0) * K + c0;
  const u16* gB = B + (bn + r0) * K + c0;
  u16* lA = As + r0 * 32 + c0;
  u16* lB = Bs + r0 * 32 + c0;
  const size_t rstep = (size_t)64 * K;

  f4v acc[4][4];
#pragma unroll
  for (int m = 0; m < 4; ++m)
#pragma unroll
    for (int n = 0; n < 4; ++n)
      acc[m][n] = f4v{0.f, 0.f, 0.f, 0.f};

  for (int k0 = 0; k0 < K; k0 += 32) {
    __syncthreads();  // previous iter's ds_reads done before overwrite
    gload16(gA + k0, lA);
    gload16(gA + rstep + k0, lA + 64 * 32);
    gload16(gB + k0, lB);
    gload16(gB + rstep + k0, lB + 64 * 32);
    __syncthreads();  // drains vmcnt -> staged data visible
    s8v af[4], bf_[4];
#pragma unroll
    for (int m = 0; m < 4; ++m)
      af[m] = *(const s8v*)(As + (wr + m * 16 + fr) * 32 + fq * 8);
#pragma unroll
    for (int n = 0; n < 4; ++n)
      bf_[n] = *(const s8v*)(Bs + (wc + n * 16 + fr) * 32 + fq * 8);
#pragma unroll
    for (int m = 0; m < 4; ++m)
#pragma unroll
      for (int n = 0; n < 4; ++n)
        acc[m][n] = __builtin_amdgcn_mfma_f32_16x16x32_bf16(af[m], bf_[n],
                                                            acc[m][n], 0, 0, 0);
  }

  // epilogue: C/D layout col=lane&15, row=(lane>>4)*4+i  [m89-verified]
#pragma unroll
  for (int m = 0; m < 4; ++m) {
    const size_t row0 = bm + wr + m * 16 + fq * 4;
#pragma unroll
    for (int n = 0; n < 4; ++n) {
      const size_t col = bn + wc + n * 16 + fr;
#pragma unroll
      for (int i = 0; i < 4; ++i)
        C[(row0 + i) * ldc + col] = f2bf(acc[m][n][i]);
    }
  }
}

// ---------------------------------------------------------------------------
// CSR build
// ---------------------------------------------------------------------------
__global__ void deg_hist(const int* __restrict__ dst, int* __restrict__ degi, int nE) {
  const int e = blockIdx.x * 256 + threadIdx.x;
  if (e < nE) atomicAdd(&degi[dst[e]], 1);
}

__global__ __launch_bounds__(1024) void scan_kernel(const int* __restrict__ degi,
                                                    int* __restrict__ offs, int n) {
  __shared__ int sums[1024];
  const int tid = threadIdx.x;
  const int C = (n + 1023) / 1024;
  const int base = tid * C;
  int local = 0;
  for (int i = 0; i < C; ++i) {
    const int idx = base + i;
    if (idx < n) local += degi[idx];
  }
  sums[tid] = local;
  __syncthreads();
  for (int off = 1; off < 1024; off <<= 1) {
    const int v = (tid >= off) ? sums[tid - off] : 0;
    __syncthreads();
    sums[tid] += v;
    __syncthreads();
  }
  int run = (tid == 0) ? 0 : sums[tid - 1];
  for (int i = 0; i < C; ++i) {
    const int idx = base + i;
    if (idx < n) { offs[idx] = run; run += degi[idx]; }
  }
  if (tid == 1023) offs[n] = sums[1023];
}

__global__ void fill_csr(const int* __restrict__ src, const int* __restrict__ dst,
                         const int* __restrict__ offs, int* __restrict__ cursor,
                         int* __restrict__ sorted_src, int nE) {
  const int e = blockIdx.x * 256 + threadIdx.x;
  if (e < nE) {
    const int d = dst[e];
    const int pos = offs[d] + atomicAdd(&cursor[d], 1);
    sorted_src[pos] = src[e];
  }
}

// ---------------------------------------------------------------------------
// h[n] = relu( mean_{e in CSR(n)} t[src_e] + bias + r[n] ), bf16 in.
// D/8 lanes per node, 8 elems each. OUTF32: fp32 out (for pooling) else bf16.
// ---------------------------------------------------------------------------
template <int D, int OUTF32>
__global__ __launch_bounds__(256) void gather_combine(
    const u16* __restrict__ t, const u16* __restrict__ r, int ldt,
    const float* __restrict__ bias, const int* __restrict__ offs,
    const int* __restrict__ ssrc, void* __restrict__ hout) {
  constexpr int LPN = D / 8;
  const int node = (int)((blockIdx.x * 256u + threadIdx.x) / LPN);
  if (node >= N_NODES) return;
  const int o = (int)(threadIdx.x % LPN) * 8;
  const int beg = offs[node], end = offs[node + 1];
  float a[8] = {0.f, 0.f, 0.f, 0.f, 0.f, 0.f, 0.f, 0.f};
  int e = beg;
  for (; e + 1 < end; e += 2) {
    const int s0 = ssrc[e], s1 = ssrc[e + 1];
    const u16x8 v0 = *(const u16x8*)(t + (size_t)s0 * ldt + o);
    const u16x8 v1 = *(const u16x8*)(t + (size_t)s1 * ldt + o);
#pragma unroll
    for (int j = 0; j < 8; ++j) a[j] += bf2f(v0[j]) + bf2f(v1[j]);
  }
  if (e < end) {
    const u16x8 v0 = *(const u16x8*)(t + (size_t)ssrc[e] * ldt + o);
#pragma unroll
    for (int j = 0; j < 8; ++j) a[j] += bf2f(v0[j]);
  }
  const float invd = 1.0f / fmaxf((float)(end - beg), 1.0f);
  const u16x8 rv = *(const u16x8*)(r + (size_t)node * ldt + o);
  float hv[8];
#pragma unroll
  for (int j = 0; j < 8; ++j)
    hv[j] = fmaxf(fmaf(a[j], invd, bias[o + j] + bf2f(rv[j])), 0.f);
  if (OUTF32) {
    float* hp = (float*)hout + (size_t)node * D + o;
    float4 x0 = make_float4(hv[0], hv[1], hv[2], hv[3]);
    float4 x1 = make_float4(hv[4], hv[5], hv[6], hv[7]);
    *(float4*)hp = x0;
    *(float4*)(hp + 4) = x1;
  } else {
    u16x8 ov;
#pragma unroll
    for (int j = 0; j < 8; ++j) ov[j] = f2bf(hv[j]);
    *(u16x8*)((u16*)hout + (size_t)node * D + o) = ov;
  }
}

// ---------------------------------------------------------------------------
// Fused pool + FC + log_softmax (batch sorted -> contiguous node ranges)
// ---------------------------------------------------------------------------
__global__ __launch_bounds__(256) void pool_final(const float* __restrict__ h,
                                                  const int* __restrict__ batch,
                                                  const float* __restrict__ Wfc,
                                                  const float* __restrict__ bfc,
                                                  float* __restrict__ out, int nNodes) {
  const int g = blockIdx.x;
  __shared__ int sbeg, send;
  if (threadIdx.x == 0) {
    int lo = 0, hi = nNodes;
    while (lo < hi) { const int mid = (lo + hi) >> 1; if (batch[mid] < g) lo = mid + 1; else hi = mid; }
    sbeg = lo;
    hi = nNodes;
    while (lo < hi) { const int mid = (lo + hi) >> 1; if (batch[mid] < g + 1) lo = mid + 1; else hi = mid; }
    send = lo;
  }
  __syncthreads();
  const int t = threadIdx.x;
  float s = 0.f;
  for (int row = sbeg; row < send; ++row) s += h[(size_t)row * HID2 + t];
  const float cnt = fmaxf((float)(send - sbeg), 1.0f);
  const float p = s / cnt;
  float d0 = p * Wfc[t];
  float d1 = p * Wfc[HID2 + t];
#pragma unroll
  for (int off = 32; off > 0; off >>= 1) {
    d0 += __shfl_down(d0, off);
    d1 += __shfl_down(d1, off);
  }
  __shared__ float r0[4], r1[4];
  const int wid = t >> 6, lane = t & 63;
  if (lane == 0) { r0[wid] = d0; r1[wid] = d1; }
  __syncthreads();
  if (t == 0) {
    const float l0 = r0[0] + r0[1] + r0[2] + r0[3] + bfc[0];
    const float l1 = r1[0] + r1[1] + r1[2] + r1[3] + bfc[1];
    const float m = fmaxf(l0, l1);
    const float lse = m + logf(expf(l0 - m) + expf(l1 - m));
    out[g * 2 + 0] = l0 - lse;
    out[g * 2 + 1] = l1 - lse;
  }
}

extern "C" void kernel_launch(void* const* d_in, const int* in_sizes, int n_in,
                              void* d_out, int out_size, void* d_ws, size_t ws_size,
                              hipStream_t stream) {
  (void)in_sizes; (void)n_in; (void)out_size; (void)ws_size;
  const float* x   = (const float*)d_in[0];
  const int* eidx  = (const int*)d_in[1];
  const int* batch = (const int*)d_in[2];
  const float* W1l = (const float*)d_in[3];
  const float* b1  = (const float*)d_in[4];
  const float* W1r = (const float*)d_in[5];
  const float* W2l = (const float*)d_in[6];
  const float* b2  = (const float*)d_in[7];
  const float* W2r = (const float*)d_in[8];
  const float* Wfc = (const float*)d_in[9];
  const float* bfc = (const float*)d_in[10];
  float* out = (float*)d_out;
  const int* src = eidx;
  const int* dst = eidx + N_EDGES;

  char* ws = (char*)d_ws;
  size_t off = 0;
  auto alloc = [&](size_t bytes) {
    char* p = ws + off;
    off += (bytes + 255) & ~(size_t)255;
    return p;
  };
  // C1: [N_PAD,1024] bf16 (t1 cols 0..511, r1 cols 512..1023); first half later reused as C2
  u16* C1   = (u16*)alloc((size_t)N_PAD * 1024 * 2);   // 102.5 MB
  u16* bufX = (u16*)alloc((size_t)N_PAD * 512 * 2);    // 51.25 MB ; later reused as h2 fp32
  u16* h1   = (u16*)alloc((size_t)N_PAD * 512 * 2);    // 51.25 MB
  u16* Wc1  = (u16*)alloc((size_t)1024 * 512 * 2);     // concat W1l|W1r
  u16* Wc2  = (u16*)alloc((size_t)512 * 512 * 2);      // concat W2l|W2r
  int* degi       = (int*)alloc((size_t)N_NODES * 4);
  int* offs       = (int*)alloc((size_t)(N_NODES + 1) * 4);
  int* cursor     = (int*)alloc((size_t)N_NODES * 4);
  int* sorted_src = (int*)alloc((size_t)N_EDGES * 4);
  u16* C2 = C1;                 // [N_PAD,512] bf16 (t2 cols 0..255, r2 cols 256..511)
  float* h2 = (float*)bufX;     // [N_NODES,256] fp32

  // ---- CSR build ----
  hipMemsetAsync(degi, 0, (size_t)N_NODES * 4, stream);
  hipMemsetAsync(cursor, 0, (size_t)N_NODES * 4, stream);
  deg_hist<<<(N_EDGES + 255) / 256, 256, 0, stream>>>(dst, degi, N_EDGES);
  scan_kernel<<<1, 1024, 0, stream>>>(degi, offs, N_NODES);
  fill_csr<<<(N_EDGES + 255) / 256, 256, 0, stream>>>(src, dst, offs, cursor,
                                                      sorted_src, N_EDGES);

  // ---- bf16 conversions ----
  cvt_f32_bf16<<<(N_NODES * (IN_DIM / 8) + 255) / 256, 256, 0, stream>>>(
      x, bufX, N_NODES * (IN_DIM / 8));
  cvt_f32_bf16<<<(HID * IN_DIM / 8 + 255) / 256, 256, 0, stream>>>(
      W1l, Wc1, HID * IN_DIM / 8);
  cvt_f32_bf16<<<(HID * IN_DIM / 8 + 255) / 256, 256, 0, stream>>>(
      W1r, Wc1 + (size_t)HID * IN_DIM, HID * IN_DIM / 8);
  cvt_f32_bf16<<<(HID2 * HID / 8 + 255) / 256, 256, 0, stream>>>(
      W2l, Wc2, HID2 * HID / 8);
  cvt_f32_bf16<<<(HID2 * HID / 8 + 255) / 256, 256, 0, stream>>>(
      W2r, Wc2 + (size_t)HID2 * HID, HID2 * HID / 8);

  // ---- layer 1: one fused GEMM [N_PAD,512] x [1024,512]^T -> [N_PAD,1024] ----
  {
    dim3 grid(N_PAD / 128, 1024 / 128);
    gemm_mfma<<<grid, 256, 0, stream>>>(bufX, Wc1, C1, IN_DIM, 1024);
  }
  gather_combine<HID, 0><<<(N_NODES + 3) / 4, 256, 0, stream>>>(
      C1, C1 + 512, 1024, b1, offs, sorted_src, h1);

  // ---- layer 2: [N_PAD,512] x [512,512]^T -> [N_PAD,512] ----
  {
    dim3 grid(N_PAD / 128, 512 / 128);
    gemm_mfma<<<grid, 256, 0, stream>>>(h1, Wc2, C2, HID, 512);
  }
  gather_combine<HID2, 1><<<(N_NODES + 7) / 8, 256, 0, stream>>>(
      C2, C2 + 256, 512, b2, offs, sorted_src, h2);

  // ---- pool + fc + log_softmax ----
  pool_final<<<NUM_GRAPHS, 256, 0, stream>>>(h2, batch, Wfc, bfc, out, N_NODES);
}

// Round 4
// 373.938 us; speedup vs baseline: 14.4227x; 1.2463x over previous
//
#include <hip/hip_runtime.h>
#include <cstdint>

#define N_NODES 50000
#define N_PAD 50048  // 391 * 128
#define N_EDGES 400000
#define IN_DIM 512
#define HID 512
#define HID2 256
#define NUM_GRAPHS 500
#define SCAN_BLOCKS 196  // ceil(50000/256)

typedef unsigned short u16;
typedef short s8v __attribute__((ext_vector_type(8)));    // 8 bf16 for MFMA A/B
typedef float f4v __attribute__((ext_vector_type(4)));    // MFMA C/D
typedef u16 u16x8 __attribute__((ext_vector_type(8)));

__device__ __forceinline__ u16 f2bf(float f) {
  union { float f; uint32_t u; } c;
  c.f = f;
  const uint32_t u = c.u;
  return (u16)((u + 0x7fffu + ((u >> 16) & 1u)) >> 16);  // RNE
}
__device__ __forceinline__ float bf2f(u16 v) {
  union { uint32_t u; float f; } c;
  c.u = ((uint32_t)v) << 16;
  return c.f;
}

// global -> LDS async, 16B per lane. LDS dest = wave-uniform base + lane*16.
__device__ __forceinline__ void gload16(const void* g, void* l) {
  __builtin_amdgcn_global_load_lds(
      (const __attribute__((address_space(1))) void*)(uintptr_t)g,
      (__attribute__((address_space(3))) void*)(uint32_t)(uintptr_t)l, 16, 0, 0);
}

// ---------------------------------------------------------------------------
// fp32 -> bf16 flat convert (8 elems/thread)
// ---------------------------------------------------------------------------
__global__ __launch_bounds__(256) void cvt_f32_bf16(const float* __restrict__ in,
                                                    u16* __restrict__ out, int n8) {
  const int i = blockIdx.x * 256 + threadIdx.x;
  if (i >= n8) return;
  const float4 a = ((const float4*)in)[2 * i];
  const float4 b = ((const float4*)in)[2 * i + 1];
  u16x8 o;
  o[0] = f2bf(a.x); o[1] = f2bf(a.y); o[2] = f2bf(a.z); o[3] = f2bf(a.w);
  o[4] = f2bf(b.x); o[5] = f2bf(b.y); o[6] = f2bf(b.z); o[7] = f2bf(b.w);
  ((u16x8*)out)[i] = o;
}

// all 4 weight matrices in one launch: 98304 groups of 8 elems = 384 blocks
__global__ __launch_bounds__(256) void cvt_weights(const float* __restrict__ W1l,
                                                   const float* __restrict__ W1r,
                                                   const float* __restrict__ W2l,
                                                   const float* __restrict__ W2r,
                                                   u16* __restrict__ Wc1,
                                                   u16* __restrict__ Wc2) {
  const int i = blockIdx.x * 256 + threadIdx.x;
  const float* src;
  u16* dstp;
  int l;
  if (i < 32768)      { src = W1l; dstp = Wc1;          l = i; }
  else if (i < 65536) { src = W1r; dstp = Wc1 + 262144; l = i - 32768; }
  else if (i < 81920) { src = W2l; dstp = Wc2;          l = i - 65536; }
  else                { src = W2r; dstp = Wc2 + 131072; l = i - 81920; }
  const float4 a = ((const float4*)src)[2 * l];
  const float4 b = ((const float4*)src)[2 * l + 1];
  u16x8 o;
  o[0] = f2bf(a.x); o[1] = f2bf(a.y); o[2] = f2bf(a.z); o[3] = f2bf(a.w);
  o[4] = f2bf(b.x); o[5] = f2bf(b.y); o[6] = f2bf(b.z); o[7] = f2bf(b.w);
  ((u16x8*)dstp)[l] = o;
}

// ---------------------------------------------------------------------------
// bf16 MFMA GEMM, m97 structure: C[M,N](bf16) = A[M,K](bf16) * B[N,K]^T(bf16)
// 128x128 tile, BK=32, 256 thr (4 waves, 2x2), 4x4 frags of 16x16x32.
// ---------------------------------------------------------------------------
__global__ __launch_bounds__(256) void gemm_mfma(const u16* __restrict__ A,
                                                 const u16* __restrict__ B,
                                                 u16* __restrict__ C,
                                                 int K, int ldc) {
  __shared__ __align__(16) u16 As[128 * 32];
  __shared__ __align__(16) u16 Bs[128 * 32];
  const int tid = threadIdx.x;
  const int lane = tid & 63;
  const int wave = tid >> 6;
  const int wr = (wave >> 1) * 64;
  const int wc = (wave & 1) * 64;
  const int fr = lane & 15;
  const int fq = lane >> 4;
  const size_t bm = (size_t)blockIdx.x * 128;
  const size_t bn = (size_t)blockIdx.y * 128;

  const int r0 = tid >> 2;
  const int c0 = (tid & 3) * 8;
  const u16* gA = A + (bm + r0) * K + c0;
  const u16* gB = B + (bn + r0) * K + c0;
  u16* lA = As + r0 * 32 + c0;
  u16* lB = Bs + r0 * 32 + c0;
  const size_t rstep = (size_t)64 * K;

  f4v acc[4][4];
#pragma unroll
  for (int m = 0; m < 4; ++m)
#pragma unroll
    for (int n = 0; n < 4; ++n)
      acc[m][n] = f4v{0.f, 0.f, 0.f, 0.f};

  for (int k0 = 0; k0 < K; k0 += 32) {
    __syncthreads();
    gload16(gA + k0, lA);
    gload16(gA + rstep + k0, lA + 64 * 32);
    gload16(gB + k0, lB);
    gload16(gB + rstep + k0, lB + 64 * 32);
    __syncthreads();
    s8v af[4], bf_[4];
#pragma unroll
    for (int m = 0; m < 4; ++m)
      af[m] = *(const s8v*)(As + (wr + m * 16 + fr) * 32 + fq * 8);
#pragma unroll
    for (int n = 0; n < 4; ++n)
      bf_[n] = *(const s8v*)(Bs + (wc + n * 16 + fr) * 32 + fq * 8);
#pragma unroll
    for (int m = 0; m < 4; ++m)
#pragma unroll
      for (int n = 0; n < 4; ++n)
        acc[m][n] = __builtin_amdgcn_mfma_f32_16x16x32_bf16(af[m], bf_[n],
                                                            acc[m][n], 0, 0, 0);
  }

#pragma unroll
  for (int m = 0; m < 4; ++m) {
    const size_t row0 = bm + wr + m * 16 + fq * 4;
#pragma unroll
    for (int n = 0; n < 4; ++n) {
      const size_t col = bn + wc + n * 16 + fr;
#pragma unroll
      for (int i = 0; i < 4; ++i)
        C[(row0 + i) * ldc + col] = f2bf(acc[m][n][i]);
    }
  }
}

// ---------------------------------------------------------------------------
// CSR build: histogram + hierarchical scan + cursor fill
// ---------------------------------------------------------------------------
__global__ void deg_hist(const int* __restrict__ dst, int* __restrict__ degi, int nE) {
  const int e = blockIdx.x * 256 + threadIdx.x;
  if (e < nE) atomicAdd(&degi[dst[e]], 1);
}

__device__ __forceinline__ int block_scan_excl(int v, int* total_out) {
  // 256-thread block: returns exclusive prefix of v; *total_out = block total
  const int lane = threadIdx.x & 63;
  const int wid = threadIdx.x >> 6;
  int s = v;
#pragma unroll
  for (int off = 1; off < 64; off <<= 1) {
    const int t = __shfl_up(s, off);
    if (lane >= off) s += t;
  }
  __shared__ int wsum[4];
  if (lane == 63) wsum[wid] = s;
  __syncthreads();
  int base = 0;
#pragma unroll
  for (int w = 0; w < 4; ++w)
    if (w < wid) base += wsum[w];
  *total_out = wsum[0] + wsum[1] + wsum[2] + wsum[3];
  return base + s - v;
}

__global__ __launch_bounds__(256) void scan_blocks(const int* __restrict__ degi,
                                                   int* __restrict__ offs,
                                                   int* __restrict__ bsum, int n) {
  const int gid = blockIdx.x * 256 + threadIdx.x;
  const int v = (gid < n) ? degi[gid] : 0;
  int total;
  const int excl = block_scan_excl(v, &total);
  if (gid < n) offs[gid] = excl;
  if (threadIdx.x == 0) bsum[blockIdx.x] = total;
}

__global__ __launch_bounds__(256) void scan_bsums(int* __restrict__ bsum, int nb) {
  const int v = (threadIdx.x < nb) ? bsum[threadIdx.x] : 0;
  int total;
  const int excl = block_scan_excl(v, &total);
  if (threadIdx.x < nb) bsum[threadIdx.x] = excl;
}

__global__ __launch_bounds__(256) void add_base(int* __restrict__ offs,
                                                const int* __restrict__ bsum,
                                                int n, int nE) {
  const int gid = blockIdx.x * 256 + threadIdx.x;
  if (gid < n) offs[gid] += bsum[blockIdx.x];
  if (gid == 0) offs[n] = nE;
}

__global__ void fill_csr(const int* __restrict__ src, const int* __restrict__ dst,
                         const int* __restrict__ offs, int* __restrict__ cursor,
                         int* __restrict__ sorted_src, int nE) {
  const int e = blockIdx.x * 256 + threadIdx.x;
  if (e < nE) {
    const int d = dst[e];
    const int pos = offs[d] + atomicAdd(&cursor[d], 1);
    sorted_src[pos] = src[e];
  }
}

// ---------------------------------------------------------------------------
// h[n] = relu( mean_{e in CSR(n)} t[src_e] + bias + r[n] ), bf16 in.
// ---------------------------------------------------------------------------
template <int D, int OUTF32>
__global__ __launch_bounds__(256) void gather_combine(
    const u16* __restrict__ t, const u16* __restrict__ r, int ldt,
    const float* __restrict__ bias, const int* __restrict__ offs,
    const int* __restrict__ ssrc, void* __restrict__ hout) {
  constexpr int LPN = D / 8;
  const int node = (int)((blockIdx.x * 256u + threadIdx.x) / LPN);
  if (node >= N_NODES) return;
  const int o = (int)(threadIdx.x % LPN) * 8;
  const int beg = offs[node], end = offs[node + 1];
  float a[8] = {0.f, 0.f, 0.f, 0.f, 0.f, 0.f, 0.f, 0.f};
  int e = beg;
  for (; e + 3 < end; e += 4) {
    const int s0 = ssrc[e], s1 = ssrc[e + 1], s2 = ssrc[e + 2], s3 = ssrc[e + 3];
    const u16x8 v0 = *(const u16x8*)(t + (size_t)s0 * ldt + o);
    const u16x8 v1 = *(const u16x8*)(t + (size_t)s1 * ldt + o);
    const u16x8 v2 = *(const u16x8*)(t + (size_t)s2 * ldt + o);
    const u16x8 v3 = *(const u16x8*)(t + (size_t)s3 * ldt + o);
#pragma unroll
    for (int j = 0; j < 8; ++j)
      a[j] += (bf2f(v0[j]) + bf2f(v1[j])) + (bf2f(v2[j]) + bf2f(v3[j]));
  }
  for (; e < end; ++e) {
    const u16x8 v0 = *(const u16x8*)(t + (size_t)ssrc[e] * ldt + o);
#pragma unroll
    for (int j = 0; j < 8; ++j) a[j] += bf2f(v0[j]);
  }
  const float invd = 1.0f / fmaxf((float)(end - beg), 1.0f);
  const u16x8 rv = *(const u16x8*)(r + (size_t)node * ldt + o);
  float hv[8];
#pragma unroll
  for (int j = 0; j < 8; ++j)
    hv[j] = fmaxf(fmaf(a[j], invd, bias[o + j] + bf2f(rv[j])), 0.f);
  if (OUTF32) {
    float* hp = (float*)hout + (size_t)node * D + o;
    *(float4*)hp = make_float4(hv[0], hv[1], hv[2], hv[3]);
    *(float4*)(hp + 4) = make_float4(hv[4], hv[5], hv[6], hv[7]);
  } else {
    u16x8 ov;
#pragma unroll
    for (int j = 0; j < 8; ++j) ov[j] = f2bf(hv[j]);
    *(u16x8*)((u16*)hout + (size_t)node * D + o) = ov;
  }
}

// ---------------------------------------------------------------------------
// Fused pool + FC + log_softmax (batch sorted -> contiguous node ranges)
// ---------------------------------------------------------------------------
__global__ __launch_bounds__(256) void pool_final(const float* __restrict__ h,
                                                  const int* __restrict__ batch,
                                                  const float* __restrict__ Wfc,
                                                  const float* __restrict__ bfc,
                                                  float* __restrict__ out, int nNodes) {
  const int g = blockIdx.x;
  __shared__ int sbeg, send;
  if (threadIdx.x == 0) {
    int lo = 0, hi = nNodes;
    while (lo < hi) { const int mid = (lo + hi) >> 1; if (batch[mid] < g) lo = mid + 1; else hi = mid; }
    sbeg = lo;
    hi = nNodes;
    while (lo < hi) { const int mid = (lo + hi) >> 1; if (batch[mid] < g + 1) lo = mid + 1; else hi = mid; }
    send = lo;
  }
  __syncthreads();
  const int t = threadIdx.x;
  float s = 0.f;
  for (int row = sbeg; row < send; ++row) s += h[(size_t)row * HID2 + t];
  const float cnt = fmaxf((float)(send - sbeg), 1.0f);
  const float p = s / cnt;
  float d0 = p * Wfc[t];
  float d1 = p * Wfc[HID2 + t];
#pragma unroll
  for (int off = 32; off > 0; off >>= 1) {
    d0 += __shfl_down(d0, off);
    d1 += __shfl_down(d1, off);
  }
  __shared__ float r0[4], r1[4];
  const int wid = t >> 6, lane = t & 63;
  if (lane == 0) { r0[wid] = d0; r1[wid] = d1; }
  __syncthreads();
  if (t == 0) {
    const float l0 = r0[0] + r0[1] + r0[2] + r0[3] + bfc[0];
    const float l1 = r1[0] + r1[1] + r1[2] + r1[3] + bfc[1];
    const float m = fmaxf(l0, l1);
    const float lse = m + logf(expf(l0 - m) + expf(l1 - m));
    out[g * 2 + 0] = l0 - lse;
    out[g * 2 + 1] = l1 - lse;
  }
}

extern "C" void kernel_launch(void* const* d_in, const int* in_sizes, int n_in,
                              void* d_out, int out_size, void* d_ws, size_t ws_size,
                              hipStream_t stream) {
  (void)in_sizes; (void)n_in; (void)out_size; (void)ws_size;
  const float* x   = (const float*)d_in[0];
  const int* eidx  = (const int*)d_in[1];
  const int* batch = (const int*)d_in[2];
  const float* W1l = (const float*)d_in[3];
  const float* b1  = (const float*)d_in[4];
  const float* W1r = (const float*)d_in[5];
  const float* W2l = (const float*)d_in[6];
  const float* b2  = (const float*)d_in[7];
  const float* W2r = (const float*)d_in[8];
  const float* Wfc = (const float*)d_in[9];
  const float* bfc = (const float*)d_in[10];
  float* out = (float*)d_out;
  const int* src = eidx;
  const int* dst = eidx + N_EDGES;

  char* ws = (char*)d_ws;
  size_t off = 0;
  auto alloc = [&](size_t bytes) {
    char* p = ws + off;
    off += (bytes + 255) & ~(size_t)255;
    return p;
  };
  u16* C1   = (u16*)alloc((size_t)N_PAD * 1024 * 2);   // GEMM1 out (t1|r1); reused as C2
  u16* bufX = (u16*)alloc((size_t)N_PAD * 512 * 2);    // x bf16; reused as h2 fp32
  u16* h1   = (u16*)alloc((size_t)N_PAD * 512 * 2);
  u16* Wc1  = (u16*)alloc((size_t)1024 * 512 * 2);
  u16* Wc2  = (u16*)alloc((size_t)512 * 512 * 2);
  int* degi       = (int*)alloc((size_t)N_NODES * 4);
  int* offs       = (int*)alloc((size_t)(N_NODES + 1) * 4);
  int* cursor     = (int*)alloc((size_t)N_NODES * 4);
  int* sorted_src = (int*)alloc((size_t)N_EDGES * 4);
  int* bsum       = (int*)alloc((size_t)SCAN_BLOCKS * 4);
  u16* C2 = C1;
  float* h2 = (float*)bufX;

  // ---- CSR build ----
  hipMemsetAsync(degi, 0, (size_t)N_NODES * 4, stream);
  hipMemsetAsync(cursor, 0, (size_t)N_NODES * 4, stream);
  deg_hist<<<(N_EDGES + 255) / 256, 256, 0, stream>>>(dst, degi, N_EDGES);
  scan_blocks<<<SCAN_BLOCKS, 256, 0, stream>>>(degi, offs, bsum, N_NODES);
  scan_bsums<<<1, 256, 0, stream>>>(bsum, SCAN_BLOCKS);
  add_base<<<SCAN_BLOCKS, 256, 0, stream>>>(offs, bsum, N_NODES, N_EDGES);
  fill_csr<<<(N_EDGES + 255) / 256, 256, 0, stream>>>(src, dst, offs, cursor,
                                                      sorted_src, N_EDGES);

  // ---- bf16 conversions ----
  cvt_f32_bf16<<<(N_NODES * (IN_DIM / 8) + 255) / 256, 256, 0, stream>>>(
      x, bufX, N_NODES * (IN_DIM / 8));
  cvt_weights<<<384, 256, 0, stream>>>(W1l, W1r, W2l, W2r, Wc1, Wc2);

  // ---- layer 1: [N_PAD,512] x [1024,512]^T -> [N_PAD,1024] ----
  {
    dim3 grid(N_PAD / 128, 1024 / 128);
    gemm_mfma<<<grid, 256, 0, stream>>>(bufX, Wc1, C1, IN_DIM, 1024);
  }
  gather_combine<HID, 0><<<(N_NODES + 3) / 4, 256, 0, stream>>>(
      C1, C1 + 512, 1024, b1, offs, sorted_src, h1);

  // ---- layer 2: [N_PAD,512] x [512,512]^T -> [N_PAD,512] ----
  {
    dim3 grid(N_PAD / 128, 512 / 128);
    gemm_mfma<<<grid, 256, 0, stream>>>(h1, Wc2, C2, HID, 512);
  }
  gather_combine<HID2, 1><<<(N_NODES + 7) / 8, 256, 0, stream>>>(
      C2, C2 + 256, 512, b2, offs, sorted_src, h2);

  // ---- pool + fc + log_softmax ----
  pool_final<<<NUM_GRAPHS, 256, 0, stream>>>(h2, batch, Wfc, bfc, out, N_NODES);
}

// Round 5
// 359.100 us; speedup vs baseline: 15.0186x; 1.0413x over previous
//
#include <hip/hip_runtime.h>
#include <cstdint>

#define N_NODES 50000
#define N_PAD 50048  // 391 * 128
#define N_EDGES 400000
#define IN_DIM 512
#define HID 512
#define HID2 256
#define NUM_GRAPHS 500
#define SCAN_BLOCKS 196  // ceil(50000/256)

typedef unsigned short u16;
typedef short s8v __attribute__((ext_vector_type(8)));    // 8 bf16 for MFMA A/B
typedef float f4v __attribute__((ext_vector_type(4)));    // MFMA C/D
typedef u16 u16x8 __attribute__((ext_vector_type(8)));

__device__ __forceinline__ u16 f2bf(float f) {
  union { float f; uint32_t u; } c;
  c.f = f;
  const uint32_t u = c.u;
  return (u16)((u + 0x7fffu + ((u >> 16) & 1u)) >> 16);  // RNE
}
__device__ __forceinline__ float bf2f(u16 v) {
  union { uint32_t u; float f; } c;
  c.u = ((uint32_t)v) << 16;
  return c.f;
}

// global -> LDS async, 16B per lane. LDS dest = wave-uniform base + lane*16.
__device__ __forceinline__ void gload16(const void* g, void* l) {
  __builtin_amdgcn_global_load_lds(
      (const __attribute__((address_space(1))) void*)(uintptr_t)g,
      (__attribute__((address_space(3))) void*)(uint32_t)(uintptr_t)l, 16, 0, 0);
}

// bijective chunked XCD swizzle (m204): contiguous id-range per XCD
__device__ __forceinline__ int xcd_swizzle(int orig, int nwg) {
  const int q = nwg >> 3, rr = nwg & 7;
  const int xcd = orig & 7, idx = orig >> 3;
  return (xcd < rr ? xcd * (q + 1) : rr * (q + 1) + (xcd - rr) * q) + idx;
}

// ---------------------------------------------------------------------------
// fp32 -> bf16 flat convert (8 elems/thread)
// ---------------------------------------------------------------------------
__global__ __launch_bounds__(256) void cvt_f32_bf16(const float* __restrict__ in,
                                                    u16* __restrict__ out, int n8) {
  const int i = blockIdx.x * 256 + threadIdx.x;
  if (i >= n8) return;
  const float4 a = ((const float4*)in)[2 * i];
  const float4 b = ((const float4*)in)[2 * i + 1];
  u16x8 o;
  o[0] = f2bf(a.x); o[1] = f2bf(a.y); o[2] = f2bf(a.z); o[3] = f2bf(a.w);
  o[4] = f2bf(b.x); o[5] = f2bf(b.y); o[6] = f2bf(b.z); o[7] = f2bf(b.w);
  ((u16x8*)out)[i] = o;
}

// all 4 weight matrices in one launch
__global__ __launch_bounds__(256) void cvt_weights(const float* __restrict__ W1l,
                                                   const float* __restrict__ W1r,
                                                   const float* __restrict__ W2l,
                                                   const float* __restrict__ W2r,
                                                   u16* __restrict__ Wc1,
                                                   u16* __restrict__ Wc2) {
  const int i = blockIdx.x * 256 + threadIdx.x;
  const float* src;
  u16* dstp;
  int l;
  if (i < 32768)      { src = W1l; dstp = Wc1;          l = i; }
  else if (i < 65536) { src = W1r; dstp = Wc1 + 262144; l = i - 32768; }
  else if (i < 81920) { src = W2l; dstp = Wc2;          l = i - 65536; }
  else                { src = W2r; dstp = Wc2 + 131072; l = i - 81920; }
  const float4 a = ((const float4*)src)[2 * l];
  const float4 b = ((const float4*)src)[2 * l + 1];
  u16x8 o;
  o[0] = f2bf(a.x); o[1] = f2bf(a.y); o[2] = f2bf(a.z); o[3] = f2bf(a.w);
  o[4] = f2bf(b.x); o[5] = f2bf(b.y); o[6] = f2bf(b.z); o[7] = f2bf(b.w);
  ((u16x8*)dstp)[l] = o;
}

// ---------------------------------------------------------------------------
// bf16 MFMA GEMM: [N_PAD,K] x [N,K]^T, N = nx*128. 1D grid, N-fast ordering +
// XCD chunk swizzle. Output split: n-tiles [0,nxHalf) -> CT, rest -> CR, both
// compact row-major with ld = nxHalf*128.
// 128x128 tile, BK=32, 256 thr (4 waves 2x2), 4x4 frags of 16x16x32.
// ---------------------------------------------------------------------------
__global__ __launch_bounds__(256) void gemm_mfma(const u16* __restrict__ A,
                                                 const u16* __restrict__ B,
                                                 u16* __restrict__ CT,
                                                 u16* __restrict__ CR,
                                                 int K, int nxLog2, int nxHalf,
                                                 int nwg) {
  __shared__ __align__(16) u16 As[128 * 32];
  __shared__ __align__(16) u16 Bs[128 * 32];
  const int id = xcd_swizzle(blockIdx.x, nwg);
  const int bx = id & ((1 << nxLog2) - 1);   // N tile (fast)
  const int by = id >> nxLog2;               // M tile
  const int tid = threadIdx.x;
  const int lane = tid & 63;
  const int wave = tid >> 6;
  const int wr = (wave >> 1) * 64;
  const int wc = (wave & 1) * 64;
  const int fr = lane & 15;
  const int fq = lane >> 4;
  const size_t bm = (size_t)by * 128;
  const size_t bn = (size_t)bx * 128;

  const int r0 = tid >> 2;
  const int c0 = (tid & 3) * 8;
  const u16* gA = A + (bm + r0) * K + c0;
  const u16* gB = B + (bn + r0) * K + c0;
  u16* lA = As + r0 * 32 + c0;
  u16* lB = Bs + r0 * 32 + c0;
  const size_t rstep = (size_t)64 * K;

  f4v acc[4][4];
#pragma unroll
  for (int m = 0; m < 4; ++m)
#pragma unroll
    for (int n = 0; n < 4; ++n)
      acc[m][n] = f4v{0.f, 0.f, 0.f, 0.f};

  for (int k0 = 0; k0 < K; k0 += 32) {
    __syncthreads();
    gload16(gA + k0, lA);
    gload16(gA + rstep + k0, lA + 64 * 32);
    gload16(gB + k0, lB);
    gload16(gB + rstep + k0, lB + 64 * 32);
    __syncthreads();
    s8v af[4], bf_[4];
#pragma unroll
    for (int m = 0; m < 4; ++m)
      af[m] = *(const s8v*)(As + (wr + m * 16 + fr) * 32 + fq * 8);
#pragma unroll
    for (int n = 0; n < 4; ++n)
      bf_[n] = *(const s8v*)(Bs + (wc + n * 16 + fr) * 32 + fq * 8);
#pragma unroll
    for (int m = 0; m < 4; ++m)
#pragma unroll
      for (int n = 0; n < 4; ++n)
        acc[m][n] = __builtin_amdgcn_mfma_f32_16x16x32_bf16(af[m], bf_[n],
                                                            acc[m][n], 0, 0, 0);
  }

  // epilogue: C/D layout col=lane&15, row=(lane>>4)*4+i  [m89-verified]
  u16* Cb = (bx < nxHalf) ? CT : CR;
  const int ldc = nxHalf * 128;
  const size_t cn0 = (size_t)(bx - (bx >= nxHalf ? nxHalf : 0)) * 128 + wc;
#pragma unroll
  for (int m = 0; m < 4; ++m) {
    const size_t row0 = bm + wr + m * 16 + fq * 4;
#pragma unroll
    for (int n = 0; n < 4; ++n) {
      const size_t col = cn0 + n * 16 + fr;
#pragma unroll
      for (int i = 0; i < 4; ++i)
        Cb[(row0 + i) * ldc + col] = f2bf(acc[m][n][i]);
    }
  }
}

// ---------------------------------------------------------------------------
// CSR build: histogram + hierarchical scan + cursor fill
// ---------------------------------------------------------------------------
__global__ void deg_hist(const int* __restrict__ dst, int* __restrict__ degi, int nE) {
  const int e = blockIdx.x * 256 + threadIdx.x;
  if (e < nE) atomicAdd(&degi[dst[e]], 1);
}

__device__ __forceinline__ int block_scan_excl(int v, int* total_out) {
  const int lane = threadIdx.x & 63;
  const int wid = threadIdx.x >> 6;
  int s = v;
#pragma unroll
  for (int off = 1; off < 64; off <<= 1) {
    const int t = __shfl_up(s, off);
    if (lane >= off) s += t;
  }
  __shared__ int wsum[4];
  if (lane == 63) wsum[wid] = s;
  __syncthreads();
  int base = 0;
#pragma unroll
  for (int w = 0; w < 4; ++w)
    if (w < wid) base += wsum[w];
  *total_out = wsum[0] + wsum[1] + wsum[2] + wsum[3];
  return base + s - v;
}

__global__ __launch_bounds__(256) void scan_blocks(const int* __restrict__ degi,
                                                   int* __restrict__ offs,
                                                   int* __restrict__ bsum, int n) {
  const int gid = blockIdx.x * 256 + threadIdx.x;
  const int v = (gid < n) ? degi[gid] : 0;
  int total;
  const int excl = block_scan_excl(v, &total);
  if (gid < n) offs[gid] = excl;
  if (threadIdx.x == 0) bsum[blockIdx.x] = total;
}

__global__ __launch_bounds__(256) void scan_bsums(int* __restrict__ bsum, int nb) {
  const int v = (threadIdx.x < nb) ? bsum[threadIdx.x] : 0;
  int total;
  const int excl = block_scan_excl(v, &total);
  if (threadIdx.x < nb) bsum[threadIdx.x] = excl;
}

__global__ __launch_bounds__(256) void add_base(int* __restrict__ offs,
                                                const int* __restrict__ bsum,
                                                int n, int nE) {
  const int gid = blockIdx.x * 256 + threadIdx.x;
  if (gid < n) offs[gid] += bsum[blockIdx.x];
  if (gid == 0) offs[n] = nE;
}

__global__ void fill_csr(const int* __restrict__ src, const int* __restrict__ dst,
                         const int* __restrict__ offs, int* __restrict__ cursor,
                         int* __restrict__ sorted_src, int nE) {
  const int e = blockIdx.x * 256 + threadIdx.x;
  if (e < nE) {
    const int d = dst[e];
    const int pos = offs[d] + atomicAdd(&cursor[d], 1);
    sorted_src[pos] = src[e];
  }
}

// ---------------------------------------------------------------------------
// h[n] = relu( mean_{e in CSR(n)} t[src_e] + bias + r[n] ), bf16 in, compact
// ld = D for both t and r. D/8 lanes per node.
// ---------------------------------------------------------------------------
template <int D, int OUTF32>
__global__ __launch_bounds__(256) void gather_combine(
    const u16* __restrict__ t, const u16* __restrict__ r,
    const float* __restrict__ bias, const int* __restrict__ offs,
    const int* __restrict__ ssrc, void* __restrict__ hout) {
  constexpr int LPN = D / 8;
  const int node = (int)((blockIdx.x * 256u + threadIdx.x) / LPN);
  if (node >= N_NODES) return;
  const int o = (int)(threadIdx.x % LPN) * 8;
  const int beg = offs[node], end = offs[node + 1];
  float a[8] = {0.f, 0.f, 0.f, 0.f, 0.f, 0.f, 0.f, 0.f};
  int e = beg;
  for (; e + 3 < end; e += 4) {
    const int s0 = ssrc[e], s1 = ssrc[e + 1], s2 = ssrc[e + 2], s3 = ssrc[e + 3];
    const u16x8 v0 = *(const u16x8*)(t + (size_t)s0 * D + o);
    const u16x8 v1 = *(const u16x8*)(t + (size_t)s1 * D + o);
    const u16x8 v2 = *(const u16x8*)(t + (size_t)s2 * D + o);
    const u16x8 v3 = *(const u16x8*)(t + (size_t)s3 * D + o);
#pragma unroll
    for (int j = 0; j < 8; ++j)
      a[j] += (bf2f(v0[j]) + bf2f(v1[j])) + (bf2f(v2[j]) + bf2f(v3[j]));
  }
  for (; e < end; ++e) {
    const u16x8 v0 = *(const u16x8*)(t + (size_t)ssrc[e] * D + o);
#pragma unroll
    for (int j = 0; j < 8; ++j) a[j] += bf2f(v0[j]);
  }
  const float invd = 1.0f / fmaxf((float)(end - beg), 1.0f);
  const u16x8 rv = *(const u16x8*)(r + (size_t)node * D + o);
  float hv[8];
#pragma unroll
  for (int j = 0; j < 8; ++j)
    hv[j] = fmaxf(fmaf(a[j], invd, bias[o + j] + bf2f(rv[j])), 0.f);
  if (OUTF32) {
    float* hp = (float*)hout + (size_t)node * D + o;
    *(float4*)hp = make_float4(hv[0], hv[1], hv[2], hv[3]);
    *(float4*)(hp + 4) = make_float4(hv[4], hv[5], hv[6], hv[7]);
  } else {
    u16x8 ov;
#pragma unroll
    for (int j = 0; j < 8; ++j) ov[j] = f2bf(hv[j]);
    *(u16x8*)((u16*)hout + (size_t)node * D + o) = ov;
  }
}

// ---------------------------------------------------------------------------
// Fused pool + FC + log_softmax (batch sorted -> contiguous node ranges)
// ---------------------------------------------------------------------------
__global__ __launch_bounds__(256) void pool_final(const float* __restrict__ h,
                                                  const int* __restrict__ batch,
                                                  const float* __restrict__ Wfc,
                                                  const float* __restrict__ bfc,
                                                  float* __restrict__ out, int nNodes) {
  const int g = blockIdx.x;
  __shared__ int sbeg, send;
  if (threadIdx.x == 0) {
    int lo = 0, hi = nNodes;
    while (lo < hi) { const int mid = (lo + hi) >> 1; if (batch[mid] < g) lo = mid + 1; else hi = mid; }
    sbeg = lo;
    hi = nNodes;
    while (lo < hi) { const int mid = (lo + hi) >> 1; if (batch[mid] < g + 1) lo = mid + 1; else hi = mid; }
    send = lo;
  }
  __syncthreads();
  const int t = threadIdx.x;
  float s = 0.f;
  for (int row = sbeg; row < send; ++row) s += h[(size_t)row * HID2 + t];
  const float cnt = fmaxf((float)(send - sbeg), 1.0f);
  const float p = s / cnt;
  float d0 = p * Wfc[t];
  float d1 = p * Wfc[HID2 + t];
#pragma unroll
  for (int off = 32; off > 0; off >>= 1) {
    d0 += __shfl_down(d0, off);
    d1 += __shfl_down(d1, off);
  }
  __shared__ float r0[4], r1[4];
  const int wid = t >> 6, lane = t & 63;
  if (lane == 0) { r0[wid] = d0; r1[wid] = d1; }
  __syncthreads();
  if (t == 0) {
    const float l0 = r0[0] + r0[1] + r0[2] + r0[3] + bfc[0];
    const float l1 = r1[0] + r1[1] + r1[2] + r1[3] + bfc[1];
    const float m = fmaxf(l0, l1);
    const float lse = m + logf(expf(l0 - m) + expf(l1 - m));
    out[g * 2 + 0] = l0 - lse;
    out[g * 2 + 1] = l1 - lse;
  }
}

extern "C" void kernel_launch(void* const* d_in, const int* in_sizes, int n_in,
                              void* d_out, int out_size, void* d_ws, size_t ws_size,
                              hipStream_t stream) {
  (void)in_sizes; (void)n_in; (void)out_size; (void)ws_size;
  const float* x   = (const float*)d_in[0];
  const int* eidx  = (const int*)d_in[1];
  const int* batch = (const int*)d_in[2];
  const float* W1l = (const float*)d_in[3];
  const float* b1  = (const float*)d_in[4];
  const float* W1r = (const float*)d_in[5];
  const float* W2l = (const float*)d_in[6];
  const float* b2  = (const float*)d_in[7];
  const float* W2r = (const float*)d_in[8];
  const float* Wfc = (const float*)d_in[9];
  const float* bfc = (const float*)d_in[10];
  float* out = (float*)d_out;
  const int* src = eidx;
  const int* dst = eidx + N_EDGES;

  char* ws = (char*)d_ws;
  size_t off = 0;
  auto alloc = [&](size_t bytes) {
    char* p = ws + off;
    off += (bytes + 255) & ~(size_t)255;
    return p;
  };
  u16* bufT = (u16*)alloc((size_t)N_PAD * 512 * 2);  // t1; reused as t2 (ld 256)
  u16* bufR = (u16*)alloc((size_t)N_PAD * 512 * 2);  // r1; reused as r2 (ld 256)
  u16* bufX = (u16*)alloc((size_t)N_PAD * 512 * 2);  // x bf16; reused as h2 fp32
  u16* h1   = (u16*)alloc((size_t)N_PAD * 512 * 2);
  u16* Wc1  = (u16*)alloc((size_t)1024 * 512 * 2);
  u16* Wc2  = (u16*)alloc((size_t)512 * 512 * 2);
  int* degi       = (int*)alloc((size_t)N_NODES * 4);
  int* offs       = (int*)alloc((size_t)(N_NODES + 1) * 4);
  int* cursor     = (int*)alloc((size_t)N_NODES * 4);
  int* sorted_src = (int*)alloc((size_t)N_EDGES * 4);
  int* bsum       = (int*)alloc((size_t)SCAN_BLOCKS * 4);
  float* h2 = (float*)bufX;

  // ---- CSR build ----
  hipMemsetAsync(degi, 0, (size_t)N_NODES * 4, stream);
  hipMemsetAsync(cursor, 0, (size_t)N_NODES * 4, stream);
  deg_hist<<<(N_EDGES + 255) / 256, 256, 0, stream>>>(dst, degi, N_EDGES);
  scan_blocks<<<SCAN_BLOCKS, 256, 0, stream>>>(degi, offs, bsum, N_NODES);
  scan_bsums<<<1, 256, 0, stream>>>(bsum, SCAN_BLOCKS);
  add_base<<<SCAN_BLOCKS, 256, 0, stream>>>(offs, bsum, N_NODES, N_EDGES);
  fill_csr<<<(N_EDGES + 255) / 256, 256, 0, stream>>>(src, dst, offs, cursor,
                                                      sorted_src, N_EDGES);

  // ---- bf16 conversions ----
  cvt_f32_bf16<<<(N_NODES * (IN_DIM / 8) + 255) / 256, 256, 0, stream>>>(
      x, bufX, N_NODES * (IN_DIM / 8));
  cvt_weights<<<384, 256, 0, stream>>>(W1l, W1r, W2l, W2r, Wc1, Wc2);

  // ---- layer 1: [N_PAD,512] x [1024,512]^T -> t1 | r1 (each [N_PAD,512]) ----
  {
    const int nwg = (N_PAD / 128) * 8;  // 3128
    gemm_mfma<<<nwg, 256, 0, stream>>>(bufX, Wc1, bufT, bufR, IN_DIM, 3, 4, nwg);
  }
  gather_combine<HID, 0><<<(N_NODES + 3) / 4, 256, 0, stream>>>(
      bufT, bufR, b1, offs, sorted_src, h1);

  // ---- layer 2: [N_PAD,512] x [512,512]^T -> t2 | r2 (each [N_PAD,256]) ----
  {
    const int nwg = (N_PAD / 128) * 4;  // 1564
    gemm_mfma<<<nwg, 256, 0, stream>>>(h1, Wc2, bufT, bufR, HID, 2, 2, nwg);
  }
  gather_combine<HID2, 1><<<(N_NODES + 7) / 8, 256, 0, stream>>>(
      bufT, bufR, b2, offs, sorted_src, h2);

  // ---- pool + fc + log_softmax ----
  pool_final<<<NUM_GRAPHS, 256, 0, stream>>>(h2, batch, Wfc, bfc, out, N_NODES);
}

// Round 6
// 350.650 us; speedup vs baseline: 15.3805x; 1.0241x over previous
//
#include <hip/hip_runtime.h>
#include <cstdint>

#define N_NODES 50000
#define N_PAD 50048  // 391 * 128
#define N_EDGES 400000
#define IN_DIM 512
#define HID 512
#define HID2 256
#define NUM_GRAPHS 500
#define SCAN_BLOCKS 196  // ceil(50000/256)

typedef unsigned short u16;
typedef short s8v __attribute__((ext_vector_type(8)));    // 8 bf16 for MFMA A/B
typedef float f4v __attribute__((ext_vector_type(4)));    // MFMA C/D
typedef u16 u16x8 __attribute__((ext_vector_type(8)));
typedef u16 u16x4 __attribute__((ext_vector_type(4)));

__device__ __forceinline__ u16 f2bf(float f) {
  union { float f; uint32_t u; } c;
  c.f = f;
  const uint32_t u = c.u;
  return (u16)((u + 0x7fffu + ((u >> 16) & 1u)) >> 16);  // RNE
}
__device__ __forceinline__ float bf2f(u16 v) {
  union { uint32_t u; float f; } c;
  c.u = ((uint32_t)v) << 16;
  return c.f;
}

// global -> LDS async, 16B per lane. LDS dest = wave-uniform base + lane*16.
__device__ __forceinline__ void gload16(const void* g, void* l) {
  __builtin_amdgcn_global_load_lds(
      (const __attribute__((address_space(1))) void*)(uintptr_t)g,
      (__attribute__((address_space(3))) void*)(uint32_t)(uintptr_t)l, 16, 0, 0);
}

// bijective chunked XCD swizzle (m204): contiguous id-range per XCD
__device__ __forceinline__ int xcd_swizzle(int orig, int nwg) {
  const int q = nwg >> 3, rr = nwg & 7;
  const int xcd = orig & 7, idx = orig >> 3;
  return (xcd < rr ? xcd * (q + 1) : rr * (q + 1) + (xcd - rr) * q) + idx;
}

// ---------------------------------------------------------------------------
// fp32 -> bf16 flat convert (8 elems/thread)
// ---------------------------------------------------------------------------
__global__ __launch_bounds__(256) void cvt_f32_bf16(const float* __restrict__ in,
                                                    u16* __restrict__ out, int n8) {
  const int i = blockIdx.x * 256 + threadIdx.x;
  if (i >= n8) return;
  const float4 a = ((const float4*)in)[2 * i];
  const float4 b = ((const float4*)in)[2 * i + 1];
  u16x8 o;
  o[0] = f2bf(a.x); o[1] = f2bf(a.y); o[2] = f2bf(a.z); o[3] = f2bf(a.w);
  o[4] = f2bf(b.x); o[5] = f2bf(b.y); o[6] = f2bf(b.z); o[7] = f2bf(b.w);
  ((u16x8*)out)[i] = o;
}

// all 4 weight matrices in one launch
__global__ __launch_bounds__(256) void cvt_weights(const float* __restrict__ W1l,
                                                   const float* __restrict__ W1r,
                                                   const float* __restrict__ W2l,
                                                   const float* __restrict__ W2r,
                                                   u16* __restrict__ Wc1,
                                                   u16* __restrict__ Wc2) {
  const int i = blockIdx.x * 256 + threadIdx.x;
  const float* src;
  u16* dstp;
  int l;
  if (i < 32768)      { src = W1l; dstp = Wc1;          l = i; }
  else if (i < 65536) { src = W1r; dstp = Wc1 + 262144; l = i - 32768; }
  else if (i < 81920) { src = W2l; dstp = Wc2;          l = i - 65536; }
  else                { src = W2r; dstp = Wc2 + 131072; l = i - 81920; }
  const float4 a = ((const float4*)src)[2 * l];
  const float4 b = ((const float4*)src)[2 * l + 1];
  u16x8 o;
  o[0] = f2bf(a.x); o[1] = f2bf(a.y); o[2] = f2bf(a.z); o[3] = f2bf(a.w);
  o[4] = f2bf(b.x); o[5] = f2bf(b.y); o[6] = f2bf(b.z); o[7] = f2bf(b.w);
  ((u16x8*)dstp)[l] = o;
}

// ---------------------------------------------------------------------------
// bf16 MFMA GEMM: [N_PAD,K] x [NX*128,K]^T. 1D grid, N-fast + XCD chunk
// swizzle. Output split: n-tiles [0,NXH) -> CT, rest -> CR (ld = NXH*128).
// 128x128 tile, BK=32, 256 thr (4 waves 2x2), 4x4 frags of 16x16x32.
// 2-deep double-buffered pipeline with counted vmcnt (T4): loads for tile
// t+2 stay in flight across the barriers; never drain vmcnt to 0 mid-loop.
// Swapped-operand MFMA -> acc holds C^T frags -> 8B packed row-major stores.
// ---------------------------------------------------------------------------
template <int K, int NXL2, int NXH>
__global__ __launch_bounds__(256) void gemm_mfma(const u16* __restrict__ A,
                                                 const u16* __restrict__ B,
                                                 u16* __restrict__ CT,
                                                 u16* __restrict__ CR,
                                                 int nwg) {
  __shared__ __align__(16) u16 As[2][128 * 32];
  __shared__ __align__(16) u16 Bs[2][128 * 32];
  const int id = xcd_swizzle(blockIdx.x, nwg);
  const int bx = id & ((1 << NXL2) - 1);   // N tile (fast)
  const int by = id >> NXL2;               // M tile
  const int tid = threadIdx.x;
  const int lane = tid & 63;
  const int wave = tid >> 6;
  const int wr = (wave >> 1) * 64;
  const int wc = (wave & 1) * 64;
  const int fr = lane & 15;
  const int fq = lane >> 4;
  const size_t bm = (size_t)by * 128;
  const size_t bn = (size_t)bx * 128;

  const int r0 = tid >> 2;
  const int c0 = (tid & 3) * 8;
  const u16* gA = A + (bm + r0) * K + c0;
  const u16* gB = B + (bn + r0) * K + c0;
  const size_t rstep = (size_t)64 * K;
  const int lofs = r0 * 32 + c0;
  constexpr int nt = K >> 5;

  auto stage = [&](int b, int kt) {
    const int k0 = kt << 5;
    gload16(gA + k0, &As[b][lofs]);
    gload16(gA + rstep + k0, &As[b][lofs + 64 * 32]);
    gload16(gB + k0, &Bs[b][lofs]);
    gload16(gB + rstep + k0, &Bs[b][lofs + 64 * 32]);
  };

  f4v acc[4][4];
#pragma unroll
  for (int m = 0; m < 4; ++m)
#pragma unroll
    for (int n = 0; n < 4; ++n)
      acc[m][n] = f4v{0.f, 0.f, 0.f, 0.f};

  // prologue: tiles 0 and 1 in flight; wait for tile 0 only
  stage(0, 0);
  stage(1, 1);
  asm volatile("s_waitcnt vmcnt(4)" ::: "memory");
  __builtin_amdgcn_s_barrier();

  for (int t = 0; t < nt; ++t) {
    const u16* curA = As[t & 1];
    const u16* curB = Bs[t & 1];
    s8v af[4], bf_[4];
#pragma unroll
    for (int m = 0; m < 4; ++m)
      af[m] = *(const s8v*)(curA + (wr + m * 16 + fr) * 32 + fq * 8);
#pragma unroll
    for (int n = 0; n < 4; ++n)
      bf_[n] = *(const s8v*)(curB + (wc + n * 16 + fr) * 32 + fq * 8);
#pragma unroll
    for (int m = 0; m < 4; ++m)
#pragma unroll
      for (int n = 0; n < 4; ++n)
        acc[m][n] = __builtin_amdgcn_mfma_f32_16x16x32_bf16(bf_[n], af[m],
                                                            acc[m][n], 0, 0, 0);
    if (t == nt - 1) break;
    __builtin_amdgcn_s_barrier();  // all waves done ds_reading buf[t&1]
    if (t + 2 < nt) {
      stage(t & 1, t + 2);         // refill freed buffer
      // oldest 4 (tile t+1) must land; newest 4 (tile t+2) stay in flight
      asm volatile("s_waitcnt vmcnt(4)" ::: "memory");
    } else {
      asm volatile("s_waitcnt vmcnt(0)" ::: "memory");
    }
    __builtin_amdgcn_s_barrier();
  }

  // epilogue (swapped layout): row = bm+wr+m*16+fr, col = cn0+n*16+fq*4+i
  // -> 4 consecutive u16 per frag -> one 8B store
  u16* Cb = (bx < NXH) ? CT : CR;
  constexpr int ldc = NXH * 128;
  const size_t cn0 = (size_t)(bx - (bx >= NXH ? NXH : 0)) * 128 + wc;
#pragma unroll
  for (int m = 0; m < 4; ++m) {
    const size_t row = bm + wr + m * 16 + fr;
#pragma unroll
    for (int n = 0; n < 4; ++n) {
      const size_t col = cn0 + n * 16 + fq * 4;
      u16x4 p;
#pragma unroll
      for (int i = 0; i < 4; ++i) p[i] = f2bf(acc[m][n][i]);
      *(u16x4*)(Cb + row * ldc + col) = p;
    }
  }
}

// ---------------------------------------------------------------------------
// CSR build: histogram + hierarchical scan + cursor fill
// ---------------------------------------------------------------------------
__global__ void deg_hist(const int* __restrict__ dst, int* __restrict__ degi, int nE) {
  const int e = blockIdx.x * 256 + threadIdx.x;
  if (e < nE) atomicAdd(&degi[dst[e]], 1);
}

__device__ __forceinline__ int block_scan_excl(int v, int* total_out) {
  const int lane = threadIdx.x & 63;
  const int wid = threadIdx.x >> 6;
  int s = v;
#pragma unroll
  for (int off = 1; off < 64; off <<= 1) {
    const int t = __shfl_up(s, off);
    if (lane >= off) s += t;
  }
  __shared__ int wsum[4];
  if (lane == 63) wsum[wid] = s;
  __syncthreads();
  int base = 0;
#pragma unroll
  for (int w = 0; w < 4; ++w)
    if (w < wid) base += wsum[w];
  *total_out = wsum[0] + wsum[1] + wsum[2] + wsum[3];
  return base + s - v;
}

__global__ __launch_bounds__(256) void scan_blocks(const int* __restrict__ degi,
                                                   int* __restrict__ offs,
                                                   int* __restrict__ bsum, int n) {
  const int gid = blockIdx.x * 256 + threadIdx.x;
  const int v = (gid < n) ? degi[gid] : 0;
  int total;
  const int excl = block_scan_excl(v, &total);
  if (gid < n) offs[gid] = excl;
  if (threadIdx.x == 0) bsum[blockIdx.x] = total;
}

__global__ __launch_bounds__(256) void scan_bsums(int* __restrict__ bsum, int nb) {
  const int v = (threadIdx.x < nb) ? bsum[threadIdx.x] : 0;
  int total;
  const int excl = block_scan_excl(v, &total);
  if (threadIdx.x < nb) bsum[threadIdx.x] = excl;
}

__global__ __launch_bounds__(256) void add_base(int* __restrict__ offs,
                                                const int* __restrict__ bsum,
                                                int n, int nE) {
  const int gid = blockIdx.x * 256 + threadIdx.x;
  if (gid < n) offs[gid] += bsum[blockIdx.x];
  if (gid == 0) offs[n] = nE;
}

__global__ void fill_csr(const int* __restrict__ src, const int* __restrict__ dst,
                         const int* __restrict__ offs, int* __restrict__ cursor,
                         int* __restrict__ sorted_src, int nE) {
  const int e = blockIdx.x * 256 + threadIdx.x;
  if (e < nE) {
    const int d = dst[e];
    const int pos = offs[d] + atomicAdd(&cursor[d], 1);
    sorted_src[pos] = src[e];
  }
}

// ---------------------------------------------------------------------------
// h[n] = relu( mean_{e in CSR(n)} t[src_e] + bias + r[n] ), bf16 in, compact
// ld = D for both t and r. D/8 lanes per node.
// ---------------------------------------------------------------------------
template <int D, int OUTF32>
__global__ __launch_bounds__(256) void gather_combine(
    const u16* __restrict__ t, const u16* __restrict__ r,
    const float* __restrict__ bias, const int* __restrict__ offs,
    const int* __restrict__ ssrc, void* __restrict__ hout) {
  constexpr int LPN = D / 8;
  const int node = (int)((blockIdx.x * 256u + threadIdx.x) / LPN);
  if (node >= N_NODES) return;
  const int o = (int)(threadIdx.x % LPN) * 8;
  const int beg = offs[node], end = offs[node + 1];
  float a[8] = {0.f, 0.f, 0.f, 0.f, 0.f, 0.f, 0.f, 0.f};
  int e = beg;
  for (; e + 3 < end; e += 4) {
    const int s0 = ssrc[e], s1 = ssrc[e + 1], s2 = ssrc[e + 2], s3 = ssrc[e + 3];
    const u16x8 v0 = *(const u16x8*)(t + (size_t)s0 * D + o);
    const u16x8 v1 = *(const u16x8*)(t + (size_t)s1 * D + o);
    const u16x8 v2 = *(const u16x8*)(t + (size_t)s2 * D + o);
    const u16x8 v3 = *(const u16x8*)(t + (size_t)s3 * D + o);
#pragma unroll
    for (int j = 0; j < 8; ++j)
      a[j] += (bf2f(v0[j]) + bf2f(v1[j])) + (bf2f(v2[j]) + bf2f(v3[j]));
  }
  for (; e < end; ++e) {
    const u16x8 v0 = *(const u16x8*)(t + (size_t)ssrc[e] * D + o);
#pragma unroll
    for (int j = 0; j < 8; ++j) a[j] += bf2f(v0[j]);
  }
  const float invd = 1.0f / fmaxf((float)(end - beg), 1.0f);
  const u16x8 rv = *(const u16x8*)(r + (size_t)node * D + o);
  float hv[8];
#pragma unroll
  for (int j = 0; j < 8; ++j)
    hv[j] = fmaxf(fmaf(a[j], invd, bias[o + j] + bf2f(rv[j])), 0.f);
  if (OUTF32) {
    float* hp = (float*)hout + (size_t)node * D + o;
    *(float4*)hp = make_float4(hv[0], hv[1], hv[2], hv[3]);
    *(float4*)(hp + 4) = make_float4(hv[4], hv[5], hv[6], hv[7]);
  } else {
    u16x8 ov;
#pragma unroll
    for (int j = 0; j < 8; ++j) ov[j] = f2bf(hv[j]);
    *(u16x8*)((u16*)hout + (size_t)node * D + o) = ov;
  }
}

// ---------------------------------------------------------------------------
// Fused pool + FC + log_softmax (batch sorted -> contiguous node ranges)
// ---------------------------------------------------------------------------
__global__ __launch_bounds__(256) void pool_final(const float* __restrict__ h,
                                                  const int* __restrict__ batch,
                                                  const float* __restrict__ Wfc,
                                                  const float* __restrict__ bfc,
                                                  float* __restrict__ out, int nNodes) {
  const int g = blockIdx.x;
  __shared__ int sbeg, send;
  if (threadIdx.x == 0) {
    int lo = 0, hi = nNodes;
    while (lo < hi) { const int mid = (lo + hi) >> 1; if (batch[mid] < g) lo = mid + 1; else hi = mid; }
    sbeg = lo;
    hi = nNodes;
    while (lo < hi) { const int mid = (lo + hi) >> 1; if (batch[mid] < g + 1) lo = mid + 1; else hi = mid; }
    send = lo;
  }
  __syncthreads();
  const int t = threadIdx.x;
  float s = 0.f;
  for (int row = sbeg; row < send; ++row) s += h[(size_t)row * HID2 + t];
  const float cnt = fmaxf((float)(send - sbeg), 1.0f);
  const float p = s / cnt;
  float d0 = p * Wfc[t];
  float d1 = p * Wfc[HID2 + t];
#pragma unroll
  for (int off = 32; off > 0; off >>= 1) {
    d0 += __shfl_down(d0, off);
    d1 += __shfl_down(d1, off);
  }
  __shared__ float r0[4], r1[4];
  const int wid = t >> 6, lane = t & 63;
  if (lane == 0) { r0[wid] = d0; r1[wid] = d1; }
  __syncthreads();
  if (t == 0) {
    const float l0 = r0[0] + r0[1] + r0[2] + r0[3] + bfc[0];
    const float l1 = r1[0] + r1[1] + r1[2] + r1[3] + bfc[1];
    const float m = fmaxf(l0, l1);
    const float lse = m + logf(expf(l0 - m) + expf(l1 - m));
    out[g * 2 + 0] = l0 - lse;
    out[g * 2 + 1] = l1 - lse;
  }
}

extern "C" void kernel_launch(void* const* d_in, const int* in_sizes, int n_in,
                              void* d_out, int out_size, void* d_ws, size_t ws_size,
                              hipStream_t stream) {
  (void)in_sizes; (void)n_in; (void)out_size; (void)ws_size;
  const float* x   = (const float*)d_in[0];
  const int* eidx  = (const int*)d_in[1];
  const int* batch = (const int*)d_in[2];
  const float* W1l = (const float*)d_in[3];
  const float* b1  = (const float*)d_in[4];
  const float* W1r = (const float*)d_in[5];
  const float* W2l = (const float*)d_in[6];
  const float* b2  = (const float*)d_in[7];
  const float* W2r = (const float*)d_in[8];
  const float* Wfc = (const float*)d_in[9];
  const float* bfc = (const float*)d_in[10];
  float* out = (float*)d_out;
  const int* src = eidx;
  const int* dst = eidx + N_EDGES;

  char* ws = (char*)d_ws;
  size_t off = 0;
  auto alloc = [&](size_t bytes) {
    char* p = ws + off;
    off += (bytes + 255) & ~(size_t)255;
    return p;
  };
  u16* bufT = (u16*)alloc((size_t)N_PAD * 512 * 2);  // t1; reused as t2 (ld 256)
  u16* bufR = (u16*)alloc((size_t)N_PAD * 512 * 2);  // r1; reused as r2 (ld 256)
  u16* bufX = (u16*)alloc((size_t)N_PAD * 512 * 2);  // x bf16; reused as h2 fp32
  u16* h1   = (u16*)alloc((size_t)N_PAD * 512 * 2);
  u16* Wc1  = (u16*)alloc((size_t)1024 * 512 * 2);
  u16* Wc2  = (u16*)alloc((size_t)512 * 512 * 2);
  int* degi   = (int*)alloc((size_t)N_NODES * 4);    // 200192 B reserved
  int* cursor = (int*)alloc((size_t)N_NODES * 4);    // adjacent to degi
  int* offs       = (int*)alloc((size_t)(N_NODES + 1) * 4);
  int* sorted_src = (int*)alloc((size_t)N_EDGES * 4);
  int* bsum       = (int*)alloc((size_t)SCAN_BLOCKS * 4);
  float* h2 = (float*)bufX;

  // ---- CSR build ----
  // degi (incl. 256B alloc padding) + cursor zeroed in one memset
  hipMemsetAsync(degi, 0, 200192 + (size_t)N_NODES * 4, stream);
  deg_hist<<<(N_EDGES + 255) / 256, 256, 0, stream>>>(dst, degi, N_EDGES);
  scan_blocks<<<SCAN_BLOCKS, 256, 0, stream>>>(degi, offs, bsum, N_NODES);
  scan_bsums<<<1, 256, 0, stream>>>(bsum, SCAN_BLOCKS);
  add_base<<<SCAN_BLOCKS, 256, 0, stream>>>(offs, bsum, N_NODES, N_EDGES);
  fill_csr<<<(N_EDGES + 255) / 256, 256, 0, stream>>>(src, dst, offs, cursor,
                                                      sorted_src, N_EDGES);

  // ---- bf16 conversions ----
  cvt_f32_bf16<<<(N_NODES * (IN_DIM / 8) + 255) / 256, 256, 0, stream>>>(
      x, bufX, N_NODES * (IN_DIM / 8));
  cvt_weights<<<384, 256, 0, stream>>>(W1l, W1r, W2l, W2r, Wc1, Wc2);

  // ---- layer 1: [N_PAD,512] x [1024,512]^T -> t1 | r1 (each [N_PAD,512]) ----
  {
    const int nwg = (N_PAD / 128) * 8;  // 3128
    gemm_mfma<IN_DIM, 3, 4><<<nwg, 256, 0, stream>>>(bufX, Wc1, bufT, bufR, nwg);
  }
  gather_combine<HID, 0><<<(N_NODES + 3) / 4, 256, 0, stream>>>(
      bufT, bufR, b1, offs, sorted_src, h1);

  // ---- layer 2: [N_PAD,512] x [512,512]^T -> t2 | r2 (each [N_PAD,256]) ----
  {
    const int nwg = (N_PAD / 128) * 4;  // 1564
    gemm_mfma<HID, 2, 2><<<nwg, 256, 0, stream>>>(h1, Wc2, bufT, bufR, nwg);
  }
  gather_combine<HID2, 1><<<(N_NODES + 7) / 8, 256, 0, stream>>>(
      bufT, bufR, b2, offs, sorted_src, h2);

  // ---- pool + fc + log_softmax ----
  pool_final<<<NUM_GRAPHS, 256, 0, stream>>>(h2, batch, Wfc, bfc, out, N_NODES);
}

// Round 7
// 349.896 us; speedup vs baseline: 15.4137x; 1.0022x over previous
//
#include <hip/hip_runtime.h>
#include <cstdint>

#define N_NODES 50000
#define N_PAD 50048  // 391 * 128
#define N_EDGES 400000
#define IN_DIM 512
#define HID 512
#define HID2 256
#define NUM_GRAPHS 500
#define SCAN_BLOCKS 196  // ceil(50000/256)

typedef unsigned short u16;
typedef short s8v __attribute__((ext_vector_type(8)));    // 8 bf16 for MFMA A/B
typedef float f4v __attribute__((ext_vector_type(4)));    // MFMA C/D
typedef u16 u16x8 __attribute__((ext_vector_type(8)));
typedef u16 u16x4 __attribute__((ext_vector_type(4)));

__device__ __forceinline__ u16 f2bf(float f) {
  union { float f; uint32_t u; } c;
  c.f = f;
  const uint32_t u = c.u;
  return (u16)((u + 0x7fffu + ((u >> 16) & 1u)) >> 16);  // RNE
}
__device__ __forceinline__ float bf2f(u16 v) {
  union { uint32_t u; float f; } c;
  c.u = ((uint32_t)v) << 16;
  return c.f;
}

// global -> LDS async, 16B per lane. LDS dest = wave-uniform base + lane*16.
__device__ __forceinline__ void gload16(const void* g, void* l) {
  __builtin_amdgcn_global_load_lds(
      (const __attribute__((address_space(1))) void*)(uintptr_t)g,
      (__attribute__((address_space(3))) void*)(uint32_t)(uintptr_t)l, 16, 0, 0);
}

// bijective chunked XCD swizzle (m204): contiguous id-range per XCD
__device__ __forceinline__ int xcd_swizzle(int orig, int nwg) {
  const int q = nwg >> 3, rr = nwg & 7;
  const int xcd = orig & 7, idx = orig >> 3;
  return (xcd < rr ? xcd * (q + 1) : rr * (q + 1) + (xcd - rr) * q) + idx;
}

// ---------------------------------------------------------------------------
// fp32 -> bf16 flat convert (8 elems/thread)
// ---------------------------------------------------------------------------
__global__ __launch_bounds__(256) void cvt_f32_bf16(const float* __restrict__ in,
                                                    u16* __restrict__ out, int n8) {
  const int i = blockIdx.x * 256 + threadIdx.x;
  if (i >= n8) return;
  const float4 a = ((const float4*)in)[2 * i];
  const float4 b = ((const float4*)in)[2 * i + 1];
  u16x8 o;
  o[0] = f2bf(a.x); o[1] = f2bf(a.y); o[2] = f2bf(a.z); o[3] = f2bf(a.w);
  o[4] = f2bf(b.x); o[5] = f2bf(b.y); o[6] = f2bf(b.z); o[7] = f2bf(b.w);
  ((u16x8*)out)[i] = o;
}

// all 4 weight matrices in one launch
__global__ __launch_bounds__(256) void cvt_weights(const float* __restrict__ W1l,
                                                   const float* __restrict__ W1r,
                                                   const float* __restrict__ W2l,
                                                   const float* __restrict__ W2r,
                                                   u16* __restrict__ Wc1,
                                                   u16* __restrict__ Wc2) {
  const int i = blockIdx.x * 256 + threadIdx.x;
  const float* src;
  u16* dstp;
  int l;
  if (i < 32768)      { src = W1l; dstp = Wc1;          l = i; }
  else if (i < 65536) { src = W1r; dstp = Wc1 + 262144; l = i - 32768; }
  else if (i < 81920) { src = W2l; dstp = Wc2;          l = i - 65536; }
  else                { src = W2r; dstp = Wc2 + 131072; l = i - 81920; }
  const float4 a = ((const float4*)src)[2 * l];
  const float4 b = ((const float4*)src)[2 * l + 1];
  u16x8 o;
  o[0] = f2bf(a.x); o[1] = f2bf(a.y); o[2] = f2bf(a.z); o[3] = f2bf(a.w);
  o[4] = f2bf(b.x); o[5] = f2bf(b.y); o[6] = f2bf(b.z); o[7] = f2bf(b.w);
  ((u16x8*)dstp)[l] = o;
}

// ---------------------------------------------------------------------------
// bf16 MFMA GEMM: [N_PAD,K] x [NX*128,K]^T. 1D grid, N-fast + XCD chunk
// swizzle. Output split: n-tiles [0,NXH) -> CT, rest -> CR (ld = NXH*128).
// 128x128 tile, BK=32, 256 thr (4 waves 2x2), 4x4 frags of 16x16x32.
// 2-deep pipeline, counted vmcnt (T4).
// LDS k-chunk swizzle (T2, rule 21 both-sides): LDS dest stays linear (gload
// requirement); the GLOBAL source chunk is permuted per lane
// (c = s ^ ((row>>1)&3)) and the read probes slot fq ^ ((fr>>1)&3). This
// spreads each 8-lane group across all 8 four-bank groups -> conflict-free.
// Swapped-operand MFMA -> acc holds C^T frags -> 8B packed row-major stores.
// ---------------------------------------------------------------------------
template <int K, int NXL2, int NXH>
__global__ __launch_bounds__(256) void gemm_mfma(const u16* __restrict__ A,
                                                 const u16* __restrict__ B,
                                                 u16* __restrict__ CT,
                                                 u16* __restrict__ CR,
                                                 int nwg) {
  __shared__ __align__(16) u16 As[2][128 * 32];
  __shared__ __align__(16) u16 Bs[2][128 * 32];
  const int id = xcd_swizzle(blockIdx.x, nwg);
  const int bx = id & ((1 << NXL2) - 1);   // N tile (fast)
  const int by = id >> NXL2;               // M tile
  const int tid = threadIdx.x;
  const int lane = tid & 63;
  const int wave = tid >> 6;
  const int wr = (wave >> 1) * 64;
  const int wc = (wave & 1) * 64;
  const int fr = lane & 15;
  const int fq = lane >> 4;
  const size_t bm = (size_t)by * 128;
  const size_t bn = (size_t)bx * 128;

  // staging: linear LDS dest (byte = tid*16); global chunk pre-swizzled
  const int r0 = tid >> 2;                              // 0..63
  const int c0 = (((tid & 3) ^ ((tid >> 3) & 3)) * 8);  // swizzled k-chunk
  const u16* gA = A + (bm + r0) * K + c0;
  const u16* gB = B + (bn + r0) * K + c0;
  const size_t rstep = (size_t)64 * K;
  const int lofs = r0 * 32 + (tid & 3) * 8;             // linear dest
  constexpr int nt = K >> 5;

  auto stage = [&](int b, int kt) {
    const int k0 = kt << 5;
    gload16(gA + k0, &As[b][lofs]);
    gload16(gA + rstep + k0, &As[b][lofs + 64 * 32]);
    gload16(gB + k0, &Bs[b][lofs]);
    gload16(gB + rstep + k0, &Bs[b][lofs + 64 * 32]);
  };

  f4v acc[4][4];
#pragma unroll
  for (int m = 0; m < 4; ++m)
#pragma unroll
    for (int n = 0; n < 4; ++n)
      acc[m][n] = f4v{0.f, 0.f, 0.f, 0.f};

  // read-side swizzle: slot = fq ^ kx, kx = (fr>>1)&3 (row-pair parity)
  const int kx = (fr >> 1) & 3;
  const int slot8 = (fq ^ kx) * 8;

  // prologue: tiles 0 and 1 in flight; wait for tile 0 only
  stage(0, 0);
  stage(1, 1);
  asm volatile("s_waitcnt vmcnt(4)" ::: "memory");
  __builtin_amdgcn_s_barrier();

  for (int t = 0; t < nt; ++t) {
    const u16* curA = As[t & 1];
    const u16* curB = Bs[t & 1];
    s8v af[4], bf_[4];
#pragma unroll
    for (int m = 0; m < 4; ++m)
      af[m] = *(const s8v*)(curA + (wr + m * 16 + fr) * 32 + slot8);
#pragma unroll
    for (int n = 0; n < 4; ++n)
      bf_[n] = *(const s8v*)(curB + (wc + n * 16 + fr) * 32 + slot8);
#pragma unroll
    for (int m = 0; m < 4; ++m)
#pragma unroll
      for (int n = 0; n < 4; ++n)
        acc[m][n] = __builtin_amdgcn_mfma_f32_16x16x32_bf16(bf_[n], af[m],
                                                            acc[m][n], 0, 0, 0);
    if (t == nt - 1) break;
    __builtin_amdgcn_s_barrier();  // all waves done ds_reading buf[t&1]
    if (t + 2 < nt) {
      stage(t & 1, t + 2);         // refill freed buffer
      asm volatile("s_waitcnt vmcnt(4)" ::: "memory");
    } else {
      asm volatile("s_waitcnt vmcnt(0)" ::: "memory");
    }
    __builtin_amdgcn_s_barrier();
  }

  // epilogue (swapped layout): row = bm+wr+m*16+fr, col = cn0+n*16+fq*4+i
  u16* Cb = (bx < NXH) ? CT : CR;
  constexpr int ldc = NXH * 128;
  const size_t cn0 = (size_t)(bx - (bx >= NXH ? NXH : 0)) * 128 + wc;
#pragma unroll
  for (int m = 0; m < 4; ++m) {
    const size_t row = bm + wr + m * 16 + fr;
#pragma unroll
    for (int n = 0; n < 4; ++n) {
      const size_t col = cn0 + n * 16 + fq * 4;
      u16x4 p;
#pragma unroll
      for (int i = 0; i < 4; ++i) p[i] = f2bf(acc[m][n][i]);
      *(u16x4*)(Cb + row * ldc + col) = p;
    }
  }
}

// ---------------------------------------------------------------------------
// CSR build: histogram + hierarchical scan + cursor fill
// ---------------------------------------------------------------------------
__global__ void deg_hist(const int* __restrict__ dst, int* __restrict__ degi, int nE) {
  const int e = blockIdx.x * 256 + threadIdx.x;
  if (e < nE) atomicAdd(&degi[dst[e]], 1);
}

__device__ __forceinline__ int block_scan_excl(int v, int* total_out) {
  const int lane = threadIdx.x & 63;
  const int wid = threadIdx.x >> 6;
  int s = v;
#pragma unroll
  for (int off = 1; off < 64; off <<= 1) {
    const int t = __shfl_up(s, off);
    if (lane >= off) s += t;
  }
  __shared__ int wsum[4];
  if (lane == 63) wsum[wid] = s;
  __syncthreads();
  int base = 0;
#pragma unroll
  for (int w = 0; w < 4; ++w)
    if (w < wid) base += wsum[w];
  *total_out = wsum[0] + wsum[1] + wsum[2] + wsum[3];
  return base + s - v;
}

__global__ __launch_bounds__(256) void scan_blocks(const int* __restrict__ degi,
                                                   int* __restrict__ offs,
                                                   int* __restrict__ bsum, int n) {
  const int gid = blockIdx.x * 256 + threadIdx.x;
  const int v = (gid < n) ? degi[gid] : 0;
  int total;
  const int excl = block_scan_excl(v, &total);
  if (gid < n) offs[gid] = excl;
  if (threadIdx.x == 0) bsum[blockIdx.x] = total;
}

__global__ __launch_bounds__(256) void scan_bsums(int* __restrict__ bsum, int nb) {
  const int v = (threadIdx.x < nb) ? bsum[threadIdx.x] : 0;
  int total;
  const int excl = block_scan_excl(v, &total);
  if (threadIdx.x < nb) bsum[threadIdx.x] = excl;
}

__global__ __launch_bounds__(256) void add_base(int* __restrict__ offs,
                                                const int* __restrict__ bsum,
                                                int n, int nE) {
  const int gid = blockIdx.x * 256 + threadIdx.x;
  if (gid < n) offs[gid] += bsum[blockIdx.x];
  if (gid == 0) offs[n] = nE;
}

__global__ void fill_csr(const int* __restrict__ src, const int* __restrict__ dst,
                         const int* __restrict__ offs, int* __restrict__ cursor,
                         int* __restrict__ sorted_src, int nE) {
  const int e = blockIdx.x * 256 + threadIdx.x;
  if (e < nE) {
    const int d = dst[e];
    const int pos = offs[d] + atomicAdd(&cursor[d], 1);
    sorted_src[pos] = src[e];
  }
}

// ---------------------------------------------------------------------------
// h[n] = relu( mean_{e in CSR(n)} t[src_e] + bias + r[n] ), bf16 in, compact
// ld = D. D/8 lanes per node; 8-deep independent-load batches (avg deg = 8).
// ---------------------------------------------------------------------------
template <int D, int OUTF32>
__global__ __launch_bounds__(256) void gather_combine(
    const u16* __restrict__ t, const u16* __restrict__ r,
    const float* __restrict__ bias, const int* __restrict__ offs,
    const int* __restrict__ ssrc, void* __restrict__ hout) {
  constexpr int LPN = D / 8;
  const int node = (int)((blockIdx.x * 256u + threadIdx.x) / LPN);
  if (node >= N_NODES) return;
  const int o = (int)(threadIdx.x % LPN) * 8;
  const int beg = offs[node], end = offs[node + 1];
  float a[8] = {0.f, 0.f, 0.f, 0.f, 0.f, 0.f, 0.f, 0.f};
  int e = beg;
  for (; e + 7 < end; e += 8) {
    u16x8 v[8];
#pragma unroll
    for (int q = 0; q < 8; ++q)
      v[q] = *(const u16x8*)(t + (size_t)ssrc[e + q] * D + o);
#pragma unroll
    for (int j = 0; j < 8; ++j)
      a[j] += ((bf2f(v[0][j]) + bf2f(v[1][j])) + (bf2f(v[2][j]) + bf2f(v[3][j]))) +
              ((bf2f(v[4][j]) + bf2f(v[5][j])) + (bf2f(v[6][j]) + bf2f(v[7][j])));
  }
  if (e + 3 < end) {
    u16x8 v[4];
#pragma unroll
    for (int q = 0; q < 4; ++q)
      v[q] = *(const u16x8*)(t + (size_t)ssrc[e + q] * D + o);
#pragma unroll
    for (int j = 0; j < 8; ++j)
      a[j] += (bf2f(v[0][j]) + bf2f(v[1][j])) + (bf2f(v[2][j]) + bf2f(v[3][j]));
    e += 4;
  }
  for (; e < end; ++e) {
    const u16x8 v0 = *(const u16x8*)(t + (size_t)ssrc[e] * D + o);
#pragma unroll
    for (int j = 0; j < 8; ++j) a[j] += bf2f(v0[j]);
  }
  const float invd = 1.0f / fmaxf((float)(end - beg), 1.0f);
  const u16x8 rv = *(const u16x8*)(r + (size_t)node * D + o);
  float hv[8];
#pragma unroll
  for (int j = 0; j < 8; ++j)
    hv[j] = fmaxf(fmaf(a[j], invd, bias[o + j] + bf2f(rv[j])), 0.f);
  if (OUTF32) {
    float* hp = (float*)hout + (size_t)node * D + o;
    *(float4*)hp = make_float4(hv[0], hv[1], hv[2], hv[3]);
    *(float4*)(hp + 4) = make_float4(hv[4], hv[5], hv[6], hv[7]);
  } else {
    u16x8 ov;
#pragma unroll
    for (int j = 0; j < 8; ++j) ov[j] = f2bf(hv[j]);
    *(u16x8*)((u16*)hout + (size_t)node * D + o) = ov;
  }
}

// ---------------------------------------------------------------------------
// Fused pool + FC + log_softmax (batch sorted -> contiguous node ranges)
// ---------------------------------------------------------------------------
__global__ __launch_bounds__(256) void pool_final(const float* __restrict__ h,
                                                  const int* __restrict__ batch,
                                                  const float* __restrict__ Wfc,
                                                  const float* __restrict__ bfc,
                                                  float* __restrict__ out, int nNodes) {
  const int g = blockIdx.x;
  __shared__ int sbeg, send;
  if (threadIdx.x == 0) {
    int lo = 0, hi = nNodes;
    while (lo < hi) { const int mid = (lo + hi) >> 1; if (batch[mid] < g) lo = mid + 1; else hi = mid; }
    sbeg = lo;
    hi = nNodes;
    while (lo < hi) { const int mid = (lo + hi) >> 1; if (batch[mid] < g + 1) lo = mid + 1; else hi = mid; }
    send = lo;
  }
  __syncthreads();
  const int t = threadIdx.x;
  float s = 0.f;
  for (int row = sbeg; row < send; ++row) s += h[(size_t)row * HID2 + t];
  const float cnt = fmaxf((float)(send - sbeg), 1.0f);
  const float p = s / cnt;
  float d0 = p * Wfc[t];
  float d1 = p * Wfc[HID2 + t];
#pragma unroll
  for (int off = 32; off > 0; off >>= 1) {
    d0 += __shfl_down(d0, off);
    d1 += __shfl_down(d1, off);
  }
  __shared__ float r0[4], r1[4];
  const int wid = t >> 6, lane = t & 63;
  if (lane == 0) { r0[wid] = d0; r1[wid] = d1; }
  __syncthreads();
  if (t == 0) {
    const float l0 = r0[0] + r0[1] + r0[2] + r0[3] + bfc[0];
    const float l1 = r1[0] + r1[1] + r1[2] + r1[3] + bfc[1];
    const float m = fmaxf(l0, l1);
    const float lse = m + logf(expf(l0 - m) + expf(l1 - m));
    out[g * 2 + 0] = l0 - lse;
    out[g * 2 + 1] = l1 - lse;
  }
}

extern "C" void kernel_launch(void* const* d_in, const int* in_sizes, int n_in,
                              void* d_out, int out_size, void* d_ws, size_t ws_size,
                              hipStream_t stream) {
  (void)in_sizes; (void)n_in; (void)out_size; (void)ws_size;
  const float* x   = (const float*)d_in[0];
  const int* eidx  = (const int*)d_in[1];
  const int* batch = (const int*)d_in[2];
  const float* W1l = (const float*)d_in[3];
  const float* b1  = (const float*)d_in[4];
  const float* W1r = (const float*)d_in[5];
  const float* W2l = (const float*)d_in[6];
  const float* b2  = (const float*)d_in[7];
  const float* W2r = (const float*)d_in[8];
  const float* Wfc = (const float*)d_in[9];
  const float* bfc = (const float*)d_in[10];
  float* out = (float*)d_out;
  const int* src = eidx;
  const int* dst = eidx + N_EDGES;

  char* ws = (char*)d_ws;
  size_t off = 0;
  auto alloc = [&](size_t bytes) {
    char* p = ws + off;
    off += (bytes + 255) & ~(size_t)255;
    return p;
  };
  u16* bufT = (u16*)alloc((size_t)N_PAD * 512 * 2);  // t1; reused as t2 (ld 256)
  u16* bufR = (u16*)alloc((size_t)N_PAD * 512 * 2);  // r1; reused as r2 (ld 256)
  u16* bufX = (u16*)alloc((size_t)N_PAD * 512 * 2);  // x bf16; reused as h2 fp32
  u16* h1   = (u16*)alloc((size_t)N_PAD * 512 * 2);
  u16* Wc1  = (u16*)alloc((size_t)1024 * 512 * 2);
  u16* Wc2  = (u16*)alloc((size_t)512 * 512 * 2);
  int* degi   = (int*)alloc((size_t)N_NODES * 4);    // 200192 B reserved
  int* cursor = (int*)alloc((size_t)N_NODES * 4);    // adjacent to degi
  int* offs       = (int*)alloc((size_t)(N_NODES + 1) * 4);
  int* sorted_src = (int*)alloc((size_t)N_EDGES * 4);
  int* bsum       = (int*)alloc((size_t)SCAN_BLOCKS * 4);
  float* h2 = (float*)bufX;

  // ---- CSR build ----
  hipMemsetAsync(degi, 0, 200192 + (size_t)N_NODES * 4, stream);
  deg_hist<<<(N_EDGES + 255) / 256, 256, 0, stream>>>(dst, degi, N_EDGES);
  scan_blocks<<<SCAN_BLOCKS, 256, 0, stream>>>(degi, offs, bsum, N_NODES);
  scan_bsums<<<1, 256, 0, stream>>>(bsum, SCAN_BLOCKS);
  add_base<<<SCAN_BLOCKS, 256, 0, stream>>>(offs, bsum, N_NODES, N_EDGES);
  fill_csr<<<(N_EDGES + 255) / 256, 256, 0, stream>>>(src, dst, offs, cursor,
                                                      sorted_src, N_EDGES);

  // ---- bf16 conversions ----
  cvt_f32_bf16<<<(N_NODES * (IN_DIM / 8) + 255) / 256, 256, 0, stream>>>(
      x, bufX, N_NODES * (IN_DIM / 8));
  cvt_weights<<<384, 256, 0, stream>>>(W1l, W1r, W2l, W2r, Wc1, Wc2);

  // ---- layer 1: [N_PAD,512] x [1024,512]^T -> t1 | r1 (each [N_PAD,512]) ----
  {
    const int nwg = (N_PAD / 128) * 8;  // 3128
    gemm_mfma<IN_DIM, 3, 4><<<nwg, 256, 0, stream>>>(bufX, Wc1, bufT, bufR, nwg);
  }
  gather_combine<HID, 0><<<(N_NODES + 3) / 4, 256, 0, stream>>>(
      bufT, bufR, b1, offs, sorted_src, h1);

  // ---- layer 2: [N_PAD,512] x [512,512]^T -> t2 | r2 (each [N_PAD,256]) ----
  {
    const int nwg = (N_PAD / 128) * 4;  // 1564
    gemm_mfma<HID, 2, 2><<<nwg, 256, 0, stream>>>(h1, Wc2, bufT, bufR, nwg);
  }
  gather_combine<HID2, 1><<<(N_NODES + 7) / 8, 256, 0, stream>>>(
      bufT, bufR, b2, offs, sorted_src, h2);

  // ---- pool + fc + log_softmax ----
  pool_final<<<NUM_GRAPHS, 256, 0, stream>>>(h2, batch, Wfc, bfc, out, N_NODES);
}